// Round 5
// baseline (1194.673 us; speedup 1.0000x reference)
//
#include <hip/hip_runtime.h>

#define N_TOK 32768
#define D_ 512
#define F_ 2048
#define E_ 8
#define M_TILE 128
#define BF_ 128
#define NSLOT_MAX 66560   // 65536 + 8*128 padding, 128-aligned per expert

typedef __attribute__((ext_vector_type(8))) short bf16x8;
typedef __attribute__((ext_vector_type(8))) unsigned short us8;
typedef __attribute__((ext_vector_type(4))) float f32x4;

__device__ __forceinline__ unsigned short f2bf(float f) {
  union { float f; unsigned u; } v; v.f = f;
  unsigned r = v.u + 0x7fffu + ((v.u >> 16) & 1u);   // RNE; inputs finite
  return (unsigned short)(r >> 16);
}

// W1 [E][D][F] f32 -> fragment-ordered bf16 W1F [E][F/16 fb][D/32 kb][64 l][8 j]:
// lane l holds W1[e][kb*32+(l>>4)*8+j][fb*16+(l&15)]
__global__ void cvtW1_k(const float* __restrict__ W1, unsigned short* __restrict__ W1F) {
  const int gw = blockIdx.x * 4 + (threadIdx.x >> 6);   // 16384 waves
  const int l  = threadIdx.x & 63;
  const int kb = gw & 15;
  const int fb = (gw >> 4) & 127;
  const int e  = gw >> 11;
  const int f  = fb * 16 + (l & 15);
  const int k0 = kb * 32 + (l >> 4) * 8;
  const float* src = W1 + ((size_t)e * D_ + k0) * F_ + f;
  us8 v;
#pragma unroll
  for (int j = 0; j < 8; ++j) v[j] = f2bf(src[(size_t)j * F_]);
  *reinterpret_cast<us8*>(W1F + ((size_t)gw * 64 + l) * 8) = v;
}

// W2 [E][F][D] f32 -> fragment-ordered bf16:
// dest[((e*64+fb)*32+db)*512 + l*8 + j] = bf16(W2[e][fb*32+(l>>4)*8+j][db*16+(l&15)])
__global__ void cvtW2_k(const float* __restrict__ W2, unsigned short* __restrict__ W2B) {
  const int gid = blockIdx.x * 256 + threadIdx.x;    // 1,048,576 total
  const int l  = gid & 63;
  const int db = (gid >> 6) & 31;
  const int fb = (gid >> 11) & 63;
  const int e  = gid >> 17;
  const int d  = db * 16 + (l & 15);
  const int f0 = fb * 32 + (l >> 4) * 8;
  const float* src = W2 + ((size_t)e * F_ + f0) * D_ + d;
  us8 v;
#pragma unroll
  for (int j = 0; j < 8; ++j) v[j] = f2bf(src[(size_t)j * D_]);
  *reinterpret_cast<us8*>(W2B + (size_t)gid * 8) = v;
}

// one wave per token: logits = x_row @ Wr, softmax fp32, top-2. NO atomics.
__global__ void router_k(const float* __restrict__ x, const float* __restrict__ Wr,
                         int* __restrict__ ridx, float* __restrict__ rw) {
  const int wid = threadIdx.x >> 6, lane = threadIdx.x & 63;
  const int t = blockIdx.x * 4 + wid;
  const float* xr = x + (size_t)t * D_ + lane * 8;
  const float4 xa = *reinterpret_cast<const float4*>(xr);
  const float4 xb = *reinterpret_cast<const float4*>(xr + 4);
  float xv[8] = {xa.x, xa.y, xa.z, xa.w, xb.x, xb.y, xb.z, xb.w};
  float lg[8] = {0, 0, 0, 0, 0, 0, 0, 0};
#pragma unroll
  for (int j = 0; j < 8; ++j) {
    const float* wr = Wr + (size_t)(lane * 8 + j) * E_;
    float4 w0 = *reinterpret_cast<const float4*>(wr);
    float4 w1 = *reinterpret_cast<const float4*>(wr + 4);
    lg[0] += xv[j] * w0.x; lg[1] += xv[j] * w0.y; lg[2] += xv[j] * w0.z; lg[3] += xv[j] * w0.w;
    lg[4] += xv[j] * w1.x; lg[5] += xv[j] * w1.y; lg[6] += xv[j] * w1.z; lg[7] += xv[j] * w1.w;
  }
#pragma unroll
  for (int off = 32; off; off >>= 1) {
#pragma unroll
    for (int q = 0; q < 8; ++q) lg[q] += __shfl_xor(lg[q], off);
  }
  if (lane == 0) {
    float m = lg[0];
#pragma unroll
    for (int q = 1; q < 8; ++q) m = fmaxf(m, lg[q]);
    float p[8]; float s = 0.f;
#pragma unroll
    for (int q = 0; q < 8; ++q) { p[q] = expf(lg[q] - m); s += p[q]; }
    float inv = 1.f / s;
    int e1 = 0;
#pragma unroll
    for (int q = 1; q < 8; ++q) if (p[q] > p[e1]) e1 = q;
    int e2 = (e1 == 0) ? 1 : 0;
#pragma unroll
    for (int q = 0; q < 8; ++q) { if (q == e1) continue; if (p[q] > p[e2]) e2 = q; }
    ridx[2 * t] = e1; ridx[2 * t + 1] = e2;
    rw[2 * t] = p[e1] * inv; rw[2 * t + 1] = p[e2] * inv;
  }
}

// single block: counts, 128-padded offsets, zero cursors
__global__ void count_k(const int* __restrict__ ridx, int* __restrict__ ctrl) {
  __shared__ int h[E_];
  const int tid = threadIdx.x;   // 1024
  if (tid < E_) h[tid] = 0;
  __syncthreads();
  int c0=0,c1=0,c2=0,c3=0,c4=0,c5=0,c6=0,c7=0;
  for (int i = tid; i < 2 * N_TOK; i += 1024) {
    int v = ridx[i];
    c0 += (v == 0); c1 += (v == 1); c2 += (v == 2); c3 += (v == 3);
    c4 += (v == 4); c5 += (v == 5); c6 += (v == 6); c7 += (v == 7);
  }
  atomicAdd(&h[0], c0); atomicAdd(&h[1], c1); atomicAdd(&h[2], c2); atomicAdd(&h[3], c3);
  atomicAdd(&h[4], c4); atomicAdd(&h[5], c5); atomicAdd(&h[6], c6); atomicAdd(&h[7], c7);
  __syncthreads();
  if (tid == 0) {
    int a = 0;
    for (int e = 0; e < E_; ++e) {
      ctrl[e] = h[e];
      ctrl[8 + e] = a;
      a += (h[e] + 127) & ~127;
      ctrl[16 + e] = 0;
    }
    ctrl[24] = a;
  }
}

// per-block LDS ranks + 8 global atomics per block
__global__ void scatter_k(const int* __restrict__ ridx, const float* __restrict__ rw,
                          int* __restrict__ ctrl, int* __restrict__ ptok,
                          float* __restrict__ pgate) {
  __shared__ int h[E_], base[E_];
  const int tid = threadIdx.x;                 // 512
  const int g = blockIdx.x * 512 + tid;        // entry id
  if (tid < E_) h[tid] = 0;
  __syncthreads();
  const int e = ridx[g];
  const int r = atomicAdd(&h[e], 1);           // LDS atomic
  __syncthreads();
  if (tid < E_) base[tid] = atomicAdd(&ctrl[16 + tid], h[tid]);
  __syncthreads();
  const int pos = ctrl[8 + e] + base[e] + r;
  ptok[pos] = g >> 1;
  pgate[pos] = rw[g];
}

// gathered activations, FRAGMENT-ORDERED: XpF[[sb][kb][64 l][8 j]]:
// lane l holds x[tok(sb*16 + (l&15))][kb*32 + (l>>4)*8 + j]. Pad slots -> 0.
__global__ void gather_k(const float* __restrict__ x, const int* __restrict__ ptok,
                         const int* __restrict__ ctrl, unsigned short* __restrict__ XpF) {
  const int sb = blockIdx.x * 4 + (threadIdx.x >> 6);   // slot-block, 4160 total
  const int l  = threadIdx.x & 63;
  const int slot = sb * 16 + (l & 15);
  bool valid = false;
#pragma unroll
  for (int e = 0; e < E_; ++e) {
    int off = ctrl[8 + e], c = ctrl[e];
    valid = valid || (slot >= off && slot < off + c);
  }
  const int tok = valid ? ptok[slot] : 0;
  const int g = l >> 4;
  unsigned short* dst = XpF + ((size_t)sb * 16) * 512 + l * 8;
#pragma unroll
  for (int kb = 0; kb < 16; ++kb) {
    us8 v = (us8){0, 0, 0, 0, 0, 0, 0, 0};
    if (valid) {
      const float* src = x + (size_t)tok * D_ + kb * 32 + g * 8;
      float4 a = *reinterpret_cast<const float4*>(src);
      float4 b = *reinterpret_cast<const float4*>(src + 4);
      v[0] = f2bf(a.x); v[1] = f2bf(a.y); v[2] = f2bf(a.z); v[3] = f2bf(a.w);
      v[4] = f2bf(b.x); v[5] = f2bf(b.y); v[6] = f2bf(b.z); v[7] = f2bf(b.w);
    }
    *reinterpret_cast<us8*>(dst + (size_t)kb * 512) = v;
  }
}

// GEMM1 + GEMM2 both read fragment-ordered operands directly from global (L2-hot,
// 1KB coalesced per wave-read). No staging LDS, no K-loop barriers. Only Hs handoff
// uses LDS (2 barriers per jF). Expert<->XCD affinity: e = gid & 7.
__global__ __launch_bounds__(512, 2) void ffn_k(
    const unsigned short* __restrict__ XpF,
    const unsigned short* __restrict__ W1F,   // [E][F/16][D/32][64][8]
    const unsigned short* __restrict__ W2B,   // [E][F/32][D/16][64][8]
    const int* __restrict__ ptok, const float* __restrict__ pgate,
    const int* __restrict__ ctrl, float* __restrict__ out) {
  const int gid = blockIdx.x;
  const int e = gid & 7;                      // XCD affinity
  const int cnt = ctrl[e];
  const int tile0 = (gid >> 3) * M_TILE;
  if (tile0 >= cnt) return;
  const int slot0 = ctrl[8 + e] + tile0;      // 128-aligned
  const int sb0 = slot0 >> 4;

  __shared__ unsigned short Hs[M_TILE][BF_ + 8];
  __shared__ int   toks[M_TILE];
  __shared__ float gts[M_TILE];

  const int tid = threadIdx.x;
  if (tid < M_TILE) {
    int slot = tile0 + tid;
    toks[tid] = (slot < cnt) ? ptok[slot0 + tid] : 0;
    gts[tid]  = (slot < cnt) ? pgate[slot0 + tid] : 0.f;
  }

  const int wid = tid >> 6, lane = tid & 63;
  const int lr = lane & 15, lg4 = lane >> 4;
  const int wm1 = wid >> 1, wn1 = wid & 1;   // GEMM1: 4x2 waves over 128x128
  const int wm2 = wid >> 2, wn2 = wid & 3;   // GEMM2: 2x4 waves over 128x512

  // A-frag stream: chunk ((sb0 + wm1*2 + mi)*16 + kb), 512 ushorts each
  const unsigned short* xa0 = XpF + ((size_t)(sb0 + wm1 * 2) * 16) * 512 + lane * 8;
  const unsigned short* w1e = W1F + (size_t)e * (F_ * D_);
  const unsigned short* W2e = W2B + (size_t)e * (F_ * D_);

  f32x4 acc[4][8];
#pragma unroll
  for (int i = 0; i < 4; ++i)
#pragma unroll
    for (int j = 0; j < 8; ++j) acc[i][j] = {0.f, 0.f, 0.f, 0.f};

  for (int jF = 0; jF < F_; jF += BF_) {
    f32x4 hacc[2][4];
#pragma unroll
    for (int i = 0; i < 2; ++i)
#pragma unroll
      for (int j = 0; j < 4; ++j) hacc[i][j] = {0.f, 0.f, 0.f, 0.f};

    // B-frag stream: chunk (((jF>>4) + wn1*4 + ni)*16 + kb)
    const unsigned short* w1b = w1e + ((size_t)((jF >> 4) + wn1 * 4) * 16) * 512 + lane * 8;

#pragma unroll
    for (int kb = 0; kb < 16; ++kb) {
      bf16x8 af[2], bw[4];
#pragma unroll
      for (int mi = 0; mi < 2; ++mi)
        af[mi] = *reinterpret_cast<const bf16x8*>(xa0 + (size_t)mi * 8192 + kb * 512);
#pragma unroll
      for (int ni = 0; ni < 4; ++ni)
        bw[ni] = *reinterpret_cast<const bf16x8*>(w1b + (size_t)ni * 8192 + kb * 512);
#pragma unroll
      for (int mi = 0; mi < 2; ++mi)
#pragma unroll
        for (int ni = 0; ni < 4; ++ni)
          hacc[mi][ni] = __builtin_amdgcn_mfma_f32_16x16x32_bf16(af[mi], bw[ni], hacc[mi][ni], 0, 0, 0);
    }

    // exact GELU -> Hs (bf16)
#pragma unroll
    for (int mi = 0; mi < 2; ++mi)
#pragma unroll
      for (int ni = 0; ni < 4; ++ni)
#pragma unroll
        for (int r = 0; r < 4; ++r) {
          float v = hacc[mi][ni][r];
          float g = 0.5f * v * (1.f + erff(v * 0.70710678118654752f));
          Hs[wm1 * 32 + mi * 16 + lg4 * 4 + r][wn1 * 64 + ni * 16 + lr] = f2bf(g);
        }
    __syncthreads();

    // GEMM2: A from Hs (padded LDS), B from W2B (global, coalesced, L2-hot)
#pragma unroll
    for (int kb2 = 0; kb2 < 4; ++kb2) {
      const int fb = (jF >> 5) + kb2;
      bf16x8 bw2[8], ah[4];
#pragma unroll
      for (int ni = 0; ni < 8; ++ni)
        bw2[ni] = *reinterpret_cast<const bf16x8*>(W2e + ((size_t)fb * 32 + wn2 * 8 + ni) * 512 + lane * 8);
#pragma unroll
      for (int mi = 0; mi < 4; ++mi)
        ah[mi] = *reinterpret_cast<const bf16x8*>(&Hs[wm2 * 64 + mi * 16 + lr][kb2 * 32 + lg4 * 8]);
#pragma unroll
      for (int mi = 0; mi < 4; ++mi)
#pragma unroll
        for (int ni = 0; ni < 8; ++ni)
          acc[mi][ni] = __builtin_amdgcn_mfma_f32_16x16x32_bf16(ah[mi], bw2[ni], acc[mi][ni], 0, 0, 0);
    }
    __syncthreads();
  }

  // epilogue: scale by gate, atomic-add (exactly 2 adds/elem -> deterministic)
  const int rowLim = cnt - tile0;
#pragma unroll
  for (int mi = 0; mi < 4; ++mi) {
#pragma unroll
    for (int r = 0; r < 4; ++r) {
      const int row = wm2 * 64 + mi * 16 + lg4 * 4 + r;
      if (row < rowLim) {
        const float gt = gts[row];
        float* orow = out + (size_t)toks[row] * D_ + wn2 * 128 + lr;
#pragma unroll
        for (int ni = 0; ni < 8; ++ni)
          atomicAdd(orow + ni * 16, gt * acc[mi][ni][r]);
      }
    }
  }
}

extern "C" void kernel_launch(void* const* d_in, const int* in_sizes, int n_in,
                              void* d_out, int out_size, void* d_ws, size_t ws_size,
                              hipStream_t stream) {
  const float* x  = (const float*)d_in[0];
  const float* Wr = (const float*)d_in[1];
  const float* W1 = (const float*)d_in[2];
  const float* W2 = (const float*)d_in[3];
  float* out = (float*)d_out;

  char* w = (char*)d_ws;
  unsigned short* W1F = (unsigned short*)(w);                    // 16 MiB frag-ordered
  unsigned short* W2B = (unsigned short*)(w + 16777216);         // 16 MiB frag-ordered
  unsigned short* XpF = (unsigned short*)(w + 33554432);         // 65 MiB frag-ordered
  int*   ridx  = (int*)  (w + 101711872);
  float* rwgt  = (float*)(w + 101974016);
  int*   ptok  = (int*)  (w + 102236160);
  float* pgate = (float*)(w + 102502400);
  int*   ctrl  = (int*)  (w + 102768640);

  cvtW1_k<<<4096, 256, 0, stream>>>(W1, W1F);
  cvtW2_k<<<4096, 256, 0, stream>>>(W2, W2B);
  router_k<<<N_TOK / 4, 256, 0, stream>>>(x, Wr, ridx, rwgt);
  count_k<<<1, 1024, 0, stream>>>(ridx, ctrl);
  scatter_k<<<N_TOK * 2 / 512, 512, 0, stream>>>(ridx, rwgt, ctrl, ptok, pgate);
  gather_k<<<NSLOT_MAX / 16 / 4, 256, 0, stream>>>(x, ptok, ctrl, XpF);
  hipMemsetAsync(out, 0, (size_t)out_size * sizeof(float), stream);
  ffn_k<<<2048, 512, 0, stream>>>(XpF, W1F, W2B, ptok, pgate, ctrl, out);
}

// Round 6
// 864.675 us; speedup vs baseline: 1.3816x; 1.3816x over previous
//
#include <hip/hip_runtime.h>

#define N_TOK 32768
#define D_ 512
#define F_ 2048
#define E_ 8
#define M_TILE 128
#define NSLOT_MAX 66560   // 65536 + 8*128 padding, 128-aligned per expert

typedef __attribute__((ext_vector_type(8))) short bf16x8;
typedef __attribute__((ext_vector_type(8))) unsigned short us8;
typedef __attribute__((ext_vector_type(4))) float f32x4;

__device__ __forceinline__ unsigned short f2bf(float f) {
  union { float f; unsigned u; } v; v.f = f;
  unsigned r = v.u + 0x7fffu + ((v.u >> 16) & 1u);   // RNE; inputs finite
  return (unsigned short)(r >> 16);
}

__device__ __forceinline__ void gload16(const void* g, void* l) {
  __builtin_amdgcn_global_load_lds((const __attribute__((address_space(1))) void*)g,
                                   (__attribute__((address_space(3))) void*)l, 16, 0, 0);
}

// W1 [E][D][F] f32 -> fragment-ordered bf16 W1F [E][F/16 fb][D/32 kb][64 l][8 j]:
// lane l holds W1[e][kb*32+(l>>4)*8+j][fb*16+(l&15)]
__global__ void cvtW1_k(const float* __restrict__ W1, unsigned short* __restrict__ W1F) {
  const int gw = blockIdx.x * 4 + (threadIdx.x >> 6);   // 16384 waves
  const int l  = threadIdx.x & 63;
  const int kb = gw & 15;
  const int fb = (gw >> 4) & 127;
  const int e  = gw >> 11;
  const int f  = fb * 16 + (l & 15);
  const int k0 = kb * 32 + (l >> 4) * 8;
  const float* src = W1 + ((size_t)e * D_ + k0) * F_ + f;
  us8 v;
#pragma unroll
  for (int j = 0; j < 8; ++j) v[j] = f2bf(src[(size_t)j * F_]);
  *reinterpret_cast<us8*>(W1F + ((size_t)gw * 64 + l) * 8) = v;
}

// W2 [E][F][D] f32 -> fragment-ordered bf16:
// dest[((e*64+fb)*32+db)*512 + l*8 + j] = bf16(W2[e][fb*32+(l>>4)*8+j][db*16+(l&15)])
__global__ void cvtW2_k(const float* __restrict__ W2, unsigned short* __restrict__ W2B) {
  const int gid = blockIdx.x * 256 + threadIdx.x;    // 1,048,576 total
  const int l  = gid & 63;
  const int db = (gid >> 6) & 31;
  const int fb = (gid >> 11) & 63;
  const int e  = gid >> 17;
  const int d  = db * 16 + (l & 15);
  const int f0 = fb * 32 + (l >> 4) * 8;
  const float* src = W2 + ((size_t)e * F_ + f0) * D_ + d;
  us8 v;
#pragma unroll
  for (int j = 0; j < 8; ++j) v[j] = f2bf(src[(size_t)j * D_]);
  *reinterpret_cast<us8*>(W2B + (size_t)gid * 8) = v;
}

// one wave per token: logits = x_row @ Wr, softmax fp32, top-2. NO atomics.
__global__ void router_k(const float* __restrict__ x, const float* __restrict__ Wr,
                         int* __restrict__ ridx, float* __restrict__ rw) {
  const int wid = threadIdx.x >> 6, lane = threadIdx.x & 63;
  const int t = blockIdx.x * 4 + wid;
  const float* xr = x + (size_t)t * D_ + lane * 8;
  const float4 xa = *reinterpret_cast<const float4*>(xr);
  const float4 xb = *reinterpret_cast<const float4*>(xr + 4);
  float xv[8] = {xa.x, xa.y, xa.z, xa.w, xb.x, xb.y, xb.z, xb.w};
  float lg[8] = {0, 0, 0, 0, 0, 0, 0, 0};
#pragma unroll
  for (int j = 0; j < 8; ++j) {
    const float* wr = Wr + (size_t)(lane * 8 + j) * E_;
    float4 w0 = *reinterpret_cast<const float4*>(wr);
    float4 w1 = *reinterpret_cast<const float4*>(wr + 4);
    lg[0] += xv[j] * w0.x; lg[1] += xv[j] * w0.y; lg[2] += xv[j] * w0.z; lg[3] += xv[j] * w0.w;
    lg[4] += xv[j] * w1.x; lg[5] += xv[j] * w1.y; lg[6] += xv[j] * w1.z; lg[7] += xv[j] * w1.w;
  }
#pragma unroll
  for (int off = 32; off; off >>= 1) {
#pragma unroll
    for (int q = 0; q < 8; ++q) lg[q] += __shfl_xor(lg[q], off);
  }
  if (lane == 0) {
    float m = lg[0];
#pragma unroll
    for (int q = 1; q < 8; ++q) m = fmaxf(m, lg[q]);
    float p[8]; float s = 0.f;
#pragma unroll
    for (int q = 0; q < 8; ++q) { p[q] = expf(lg[q] - m); s += p[q]; }
    float inv = 1.f / s;
    int e1 = 0;
#pragma unroll
    for (int q = 1; q < 8; ++q) if (p[q] > p[e1]) e1 = q;
    int e2 = (e1 == 0) ? 1 : 0;
#pragma unroll
    for (int q = 0; q < 8; ++q) { if (q == e1) continue; if (p[q] > p[e2]) e2 = q; }
    ridx[2 * t] = e1; ridx[2 * t + 1] = e2;
    rw[2 * t] = p[e1] * inv; rw[2 * t + 1] = p[e2] * inv;
  }
}

// single block: counts, 128-padded offsets, zero cursors
__global__ void count_k(const int* __restrict__ ridx, int* __restrict__ ctrl) {
  __shared__ int h[E_];
  const int tid = threadIdx.x;   // 1024
  if (tid < E_) h[tid] = 0;
  __syncthreads();
  int c0=0,c1=0,c2=0,c3=0,c4=0,c5=0,c6=0,c7=0;
  for (int i = tid; i < 2 * N_TOK; i += 1024) {
    int v = ridx[i];
    c0 += (v == 0); c1 += (v == 1); c2 += (v == 2); c3 += (v == 3);
    c4 += (v == 4); c5 += (v == 5); c6 += (v == 6); c7 += (v == 7);
  }
  atomicAdd(&h[0], c0); atomicAdd(&h[1], c1); atomicAdd(&h[2], c2); atomicAdd(&h[3], c3);
  atomicAdd(&h[4], c4); atomicAdd(&h[5], c5); atomicAdd(&h[6], c6); atomicAdd(&h[7], c7);
  __syncthreads();
  if (tid == 0) {
    int a = 0;
    for (int e = 0; e < E_; ++e) {
      ctrl[e] = h[e];
      ctrl[8 + e] = a;
      a += (h[e] + 127) & ~127;
      ctrl[16 + e] = 0;
    }
    ctrl[24] = a;
  }
}

// per-block LDS ranks + 8 global atomics per block
__global__ void scatter_k(const int* __restrict__ ridx, const float* __restrict__ rw,
                          int* __restrict__ ctrl, int* __restrict__ ptok,
                          float* __restrict__ pgate) {
  __shared__ int h[E_], base[E_];
  const int tid = threadIdx.x;                 // 512
  const int g = blockIdx.x * 512 + tid;        // entry id
  if (tid < E_) h[tid] = 0;
  __syncthreads();
  const int e = ridx[g];
  const int r = atomicAdd(&h[e], 1);           // LDS atomic
  __syncthreads();
  if (tid < E_) base[tid] = atomicAdd(&ctrl[16 + tid], h[tid]);
  __syncthreads();
  const int pos = ctrl[8 + e] + base[e] + r;
  ptok[pos] = g >> 1;
  pgate[pos] = rw[g];
}

// gathered activations, FRAGMENT-ORDERED: XpF[sb][kb][64 l][8 j]:
// lane l holds x[tok(sb*16 + (l&15))][kb*32 + (l>>4)*8 + j]. Pad slots -> 0.
__global__ void gather_k(const float* __restrict__ x, const int* __restrict__ ptok,
                         const int* __restrict__ ctrl, unsigned short* __restrict__ XpF) {
  const int sb = blockIdx.x * 4 + (threadIdx.x >> 6);   // slot-block, 4160 total
  const int l  = threadIdx.x & 63;
  const int slot = sb * 16 + (l & 15);
  bool valid = false;
#pragma unroll
  for (int e = 0; e < E_; ++e) {
    int off = ctrl[8 + e], c = ctrl[e];
    valid = valid || (slot >= off && slot < off + c);
  }
  const int tok = valid ? ptok[slot] : 0;
  const int g = l >> 4;
  unsigned short* dst = XpF + ((size_t)sb * 16) * 512 + l * 8;
#pragma unroll
  for (int kb = 0; kb < 16; ++kb) {
    us8 v = (us8){0, 0, 0, 0, 0, 0, 0, 0};
    if (valid) {
      const float* src = x + (size_t)tok * D_ + kb * 32 + g * 8;
      float4 a = *reinterpret_cast<const float4*>(src);
      float4 b = *reinterpret_cast<const float4*>(src + 4);
      v[0] = f2bf(a.x); v[1] = f2bf(a.y); v[2] = f2bf(a.z); v[3] = f2bf(a.w);
      v[4] = f2bf(b.x); v[5] = f2bf(b.y); v[6] = f2bf(b.z); v[7] = f2bf(b.w);
    }
    *reinterpret_cast<us8*>(dst + (size_t)kb * 512) = v;
  }
}

// X panel LDS-RESIDENT (staged once, 128 KB, frag-chunk linear = DMA-coalesced AND
// conflict-free ds_read). GEMM1: A from LDS, B (W1F) direct from global (L2-hot).
// H handoff via XOR-swizzled Hs[128][128]. GEMM2: A from Hs, B (W2B) direct global.
// No barriers in GEMM1 K-loop; 2 barriers per jF (16 jF iters). e = gid&7 XCD affinity.
__global__ __launch_bounds__(512, 2) void ffn_k(
    const unsigned short* __restrict__ XpF,
    const unsigned short* __restrict__ W1F,   // [E][F/16][D/32][64][8]
    const unsigned short* __restrict__ W2B,   // [E][F/32][D/16][64][8]
    const int* __restrict__ ptok, const float* __restrict__ pgate,
    const int* __restrict__ ctrl, float* __restrict__ out) {
  const int gid = blockIdx.x;
  const int e = gid & 7;                      // XCD affinity
  const int cnt = ctrl[e];
  const int tile0 = (gid >> 3) * M_TILE;
  if (tile0 >= cnt) return;
  const int slot0 = ctrl[8 + e] + tile0;      // 128-aligned
  const int sb0 = slot0 >> 4;

  __shared__ unsigned short Xs[65536];        // 128 KB: chunks [sb_local*16+kb][lane*8]
  __shared__ unsigned short Hs[16384];        // 32 KB: [row][chunk^(row&15)][8]

  const int tid = threadIdx.x;
  const int wid = tid >> 6, lane = tid & 63;
  const int lr = lane & 15, lg4 = lane >> 4;
  const int wm = wid >> 2, wn = wid & 3;      // 2m x 4n waves (both GEMMs)

  // ---- stage X panel once: 128 contiguous KB, linear DMA
  {
    const char* xsrc = (const char*)(XpF + (size_t)sb0 * 8192);
#pragma unroll
    for (int i = 0; i < 16; ++i) {
      const int o = (i * 512 + tid) * 16;
      gload16(xsrc + o, (char*)Xs + o);
    }
  }
  asm volatile("s_waitcnt vmcnt(0)" ::: "memory");
  __syncthreads();

  const unsigned short* w1e = W1F + (size_t)e * (F_ * D_);
  const unsigned short* W2e = W2B + (size_t)e * (F_ * D_);

  f32x4 acc[4][8];
#pragma unroll
  for (int i = 0; i < 4; ++i)
#pragma unroll
    for (int j = 0; j < 8; ++j) acc[i][j] = {0.f, 0.f, 0.f, 0.f};

  for (int jF = 0; jF < F_; jF += 128) {
    f32x4 hacc[4][2];
#pragma unroll
    for (int i = 0; i < 4; ++i)
#pragma unroll
      for (int j = 0; j < 2; ++j) hacc[i][j] = {0.f, 0.f, 0.f, 0.f};

    // wave covers f-frags fb = jF/16 + wn*2 + {0,1}
    const unsigned short* w1b = w1e + ((size_t)((jF >> 4) + wn * 2) * 16) * 512 + lane * 8;

#pragma unroll
    for (int kb = 0; kb < 16; ++kb) {
      bf16x8 bw[2], af[4];
#pragma unroll
      for (int ni = 0; ni < 2; ++ni)
        bw[ni] = *reinterpret_cast<const bf16x8*>(w1b + ((size_t)ni * 16 + kb) * 512);
#pragma unroll
      for (int mi = 0; mi < 4; ++mi)
        af[mi] = *reinterpret_cast<const bf16x8*>(&Xs[((wm * 4 + mi) * 16 + kb) * 512 + lane * 8]);
#pragma unroll
      for (int mi = 0; mi < 4; ++mi)
#pragma unroll
        for (int ni = 0; ni < 2; ++ni)
          hacc[mi][ni] = __builtin_amdgcn_mfma_f32_16x16x32_bf16(af[mi], bw[ni], hacc[mi][ni], 0, 0, 0);
    }

    // ---- exact GELU -> Hs (bf16), 16B-chunk XOR swizzle (both sides)
#pragma unroll
    for (int mi = 0; mi < 4; ++mi)
#pragma unroll
      for (int ni = 0; ni < 2; ++ni)
#pragma unroll
        for (int r = 0; r < 4; ++r) {
          float v = hacc[mi][ni][r];
          float g = 0.5f * v * (1.f + erff(v * 0.70710678118654752f));
          const int row = wm * 64 + mi * 16 + lg4 * 4 + r;
          const int col = wn * 32 + ni * 16 + lr;
          const int ch = (col >> 3) ^ (row & 15);
          Hs[row * 128 + ch * 8 + (col & 7)] = f2bf(g);
        }
    __syncthreads();

    // ---- GEMM2: A from Hs (swizzled read, ~2-way), B from W2B global
#pragma unroll
    for (int kb2 = 0; kb2 < 4; ++kb2) {
      const int fb = (jF >> 5) + kb2;
      bf16x8 bw2[8], ah[4];
#pragma unroll
      for (int ni = 0; ni < 8; ++ni)
        bw2[ni] = *reinterpret_cast<const bf16x8*>(W2e + ((size_t)fb * 32 + wn * 8 + ni) * 512 + lane * 8);
#pragma unroll
      for (int mi = 0; mi < 4; ++mi) {
        const int row = wm * 64 + mi * 16 + lr;
        const int ch = (kb2 * 4 + lg4) ^ (row & 15);
        ah[mi] = *reinterpret_cast<const bf16x8*>(&Hs[row * 128 + ch * 8]);
      }
#pragma unroll
      for (int mi = 0; mi < 4; ++mi)
#pragma unroll
        for (int ni = 0; ni < 8; ++ni)
          acc[mi][ni] = __builtin_amdgcn_mfma_f32_16x16x32_bf16(ah[mi], bw2[ni], acc[mi][ni], 0, 0, 0);
    }
    __syncthreads();
  }

  // ---- epilogue: gate from global, atomic-add (exactly 2 adds/elem -> deterministic)
  const int rowLim = cnt - tile0;
#pragma unroll
  for (int mi = 0; mi < 4; ++mi) {
#pragma unroll
    for (int r = 0; r < 4; ++r) {
      const int row = wm * 64 + mi * 16 + lg4 * 4 + r;
      if (row < rowLim) {
        const int tok = ptok[slot0 + row];
        const float gt = pgate[slot0 + row];
        float* orow = out + (size_t)tok * D_ + wn * 128 + lr;
#pragma unroll
        for (int ni = 0; ni < 8; ++ni)
          atomicAdd(orow + ni * 16, gt * acc[mi][ni][r]);
      }
    }
  }
}

extern "C" void kernel_launch(void* const* d_in, const int* in_sizes, int n_in,
                              void* d_out, int out_size, void* d_ws, size_t ws_size,
                              hipStream_t stream) {
  const float* x  = (const float*)d_in[0];
  const float* Wr = (const float*)d_in[1];
  const float* W1 = (const float*)d_in[2];
  const float* W2 = (const float*)d_in[3];
  float* out = (float*)d_out;

  char* w = (char*)d_ws;
  unsigned short* W1F = (unsigned short*)(w);                    // 16 MiB frag-ordered
  unsigned short* W2B = (unsigned short*)(w + 16777216);         // 16 MiB frag-ordered
  unsigned short* XpF = (unsigned short*)(w + 33554432);         // 65 MiB frag-ordered
  int*   ridx  = (int*)  (w + 101711872);
  float* rwgt  = (float*)(w + 101974016);
  int*   ptok  = (int*)  (w + 102236160);
  float* pgate = (float*)(w + 102502400);
  int*   ctrl  = (int*)  (w + 102768640);

  cvtW1_k<<<4096, 256, 0, stream>>>(W1, W1F);
  cvtW2_k<<<4096, 256, 0, stream>>>(W2, W2B);
  router_k<<<N_TOK / 4, 256, 0, stream>>>(x, Wr, ridx, rwgt);
  count_k<<<1, 1024, 0, stream>>>(ridx, ctrl);
  scatter_k<<<N_TOK * 2 / 512, 512, 0, stream>>>(ridx, rwgt, ctrl, ptok, pgate);
  gather_k<<<NSLOT_MAX / 16 / 4, 256, 0, stream>>>(x, ptok, ctrl, XpF);
  hipMemsetAsync(out, 0, (size_t)out_size * sizeof(float), stream);
  ffn_k<<<2048, 512, 0, stream>>>(XpF, W1F, W2B, ptok, pgate, ctrl, out);
}

// Round 7
// 754.876 us; speedup vs baseline: 1.5826x; 1.1455x over previous
//
#include <hip/hip_runtime.h>

#define N_TOK 32768
#define D_ 512
#define F_ 2048
#define E_ 8
#define M_TILE 64
#define NSLOT_MAX 66560   // 65536 + 8*128 padding, 128-aligned per expert

typedef __attribute__((ext_vector_type(8))) short bf16x8;
typedef __attribute__((ext_vector_type(8))) unsigned short us8;
typedef __attribute__((ext_vector_type(4))) float f32x4;

__device__ __forceinline__ unsigned short f2bf(float f) {
  union { float f; unsigned u; } v; v.f = f;
  unsigned r = v.u + 0x7fffu + ((v.u >> 16) & 1u);   // RNE; inputs finite
  return (unsigned short)(r >> 16);
}

__device__ __forceinline__ void gload16(const void* g, void* l) {
  __builtin_amdgcn_global_load_lds((const __attribute__((address_space(1))) void*)g,
                                   (__attribute__((address_space(3))) void*)l, 16, 0, 0);
}

// W1 [E][D][F] f32 -> fragment-ordered bf16 W1F [E][F/16 fb][D/32 kb][64 l][8 j]:
// lane l holds W1[e][kb*32+(l>>4)*8+j][fb*16+(l&15)]
__global__ void cvtW1_k(const float* __restrict__ W1, unsigned short* __restrict__ W1F) {
  const int gw = blockIdx.x * 4 + (threadIdx.x >> 6);   // 16384 waves
  const int l  = threadIdx.x & 63;
  const int kb = gw & 15;
  const int fb = (gw >> 4) & 127;
  const int e  = gw >> 11;
  const int f  = fb * 16 + (l & 15);
  const int k0 = kb * 32 + (l >> 4) * 8;
  const float* src = W1 + ((size_t)e * D_ + k0) * F_ + f;
  us8 v;
#pragma unroll
  for (int j = 0; j < 8; ++j) v[j] = f2bf(src[(size_t)j * F_]);
  *reinterpret_cast<us8*>(W1F + ((size_t)gw * 64 + l) * 8) = v;
}

// W2 [E][F][D] f32 -> fragment-ordered bf16:
// dest[((e*64+fb)*32+db)*512 + l*8 + j] = bf16(W2[e][fb*32+(l>>4)*8+j][db*16+(l&15)])
__global__ void cvtW2_k(const float* __restrict__ W2, unsigned short* __restrict__ W2B) {
  const int gid = blockIdx.x * 256 + threadIdx.x;    // 1,048,576 total
  const int l  = gid & 63;
  const int db = (gid >> 6) & 31;
  const int fb = (gid >> 11) & 63;
  const int e  = gid >> 17;
  const int d  = db * 16 + (l & 15);
  const int f0 = fb * 32 + (l >> 4) * 8;
  const float* src = W2 + ((size_t)e * F_ + f0) * D_ + d;
  us8 v;
#pragma unroll
  for (int j = 0; j < 8; ++j) v[j] = f2bf(src[(size_t)j * D_]);
  *reinterpret_cast<us8*>(W2B + (size_t)gid * 8) = v;
}

// one wave per token: logits = x_row @ Wr, softmax fp32, top-2. NO atomics.
__global__ void router_k(const float* __restrict__ x, const float* __restrict__ Wr,
                         int* __restrict__ ridx, float* __restrict__ rw) {
  const int wid = threadIdx.x >> 6, lane = threadIdx.x & 63;
  const int t = blockIdx.x * 4 + wid;
  const float* xr = x + (size_t)t * D_ + lane * 8;
  const float4 xa = *reinterpret_cast<const float4*>(xr);
  const float4 xb = *reinterpret_cast<const float4*>(xr + 4);
  float xv[8] = {xa.x, xa.y, xa.z, xa.w, xb.x, xb.y, xb.z, xb.w};
  float lg[8] = {0, 0, 0, 0, 0, 0, 0, 0};
#pragma unroll
  for (int j = 0; j < 8; ++j) {
    const float* wr = Wr + (size_t)(lane * 8 + j) * E_;
    float4 w0 = *reinterpret_cast<const float4*>(wr);
    float4 w1 = *reinterpret_cast<const float4*>(wr + 4);
    lg[0] += xv[j] * w0.x; lg[1] += xv[j] * w0.y; lg[2] += xv[j] * w0.z; lg[3] += xv[j] * w0.w;
    lg[4] += xv[j] * w1.x; lg[5] += xv[j] * w1.y; lg[6] += xv[j] * w1.z; lg[7] += xv[j] * w1.w;
  }
#pragma unroll
  for (int off = 32; off; off >>= 1) {
#pragma unroll
    for (int q = 0; q < 8; ++q) lg[q] += __shfl_xor(lg[q], off);
  }
  if (lane == 0) {
    float m = lg[0];
#pragma unroll
    for (int q = 1; q < 8; ++q) m = fmaxf(m, lg[q]);
    float p[8]; float s = 0.f;
#pragma unroll
    for (int q = 0; q < 8; ++q) { p[q] = expf(lg[q] - m); s += p[q]; }
    float inv = 1.f / s;
    int e1 = 0;
#pragma unroll
    for (int q = 1; q < 8; ++q) if (p[q] > p[e1]) e1 = q;
    int e2 = (e1 == 0) ? 1 : 0;
#pragma unroll
    for (int q = 0; q < 8; ++q) { if (q == e1) continue; if (p[q] > p[e2]) e2 = q; }
    ridx[2 * t] = e1; ridx[2 * t + 1] = e2;
    rw[2 * t] = p[e1] * inv; rw[2 * t + 1] = p[e2] * inv;
  }
}

// single block: counts, 128-padded offsets, zero cursors
__global__ void count_k(const int* __restrict__ ridx, int* __restrict__ ctrl) {
  __shared__ int h[E_];
  const int tid = threadIdx.x;   // 1024
  if (tid < E_) h[tid] = 0;
  __syncthreads();
  int c0=0,c1=0,c2=0,c3=0,c4=0,c5=0,c6=0,c7=0;
  for (int i = tid; i < 2 * N_TOK; i += 1024) {
    int v = ridx[i];
    c0 += (v == 0); c1 += (v == 1); c2 += (v == 2); c3 += (v == 3);
    c4 += (v == 4); c5 += (v == 5); c6 += (v == 6); c7 += (v == 7);
  }
  atomicAdd(&h[0], c0); atomicAdd(&h[1], c1); atomicAdd(&h[2], c2); atomicAdd(&h[3], c3);
  atomicAdd(&h[4], c4); atomicAdd(&h[5], c5); atomicAdd(&h[6], c6); atomicAdd(&h[7], c7);
  __syncthreads();
  if (tid == 0) {
    int a = 0;
    for (int e = 0; e < E_; ++e) {
      ctrl[e] = h[e];
      ctrl[8 + e] = a;
      a += (h[e] + 127) & ~127;
      ctrl[16 + e] = 0;
    }
    ctrl[24] = a;
  }
}

// per-block LDS ranks + 8 global atomics per block
__global__ void scatter_k(const int* __restrict__ ridx, const float* __restrict__ rw,
                          int* __restrict__ ctrl, int* __restrict__ ptok,
                          float* __restrict__ pgate) {
  __shared__ int h[E_], base[E_];
  const int tid = threadIdx.x;                 // 512
  const int g = blockIdx.x * 512 + tid;        // entry id
  if (tid < E_) h[tid] = 0;
  __syncthreads();
  const int e = ridx[g];
  const int r = atomicAdd(&h[e], 1);           // LDS atomic
  __syncthreads();
  if (tid < E_) base[tid] = atomicAdd(&ctrl[16 + tid], h[tid]);
  __syncthreads();
  const int pos = ctrl[8 + e] + base[e] + r;
  ptok[pos] = g >> 1;
  pgate[pos] = rw[g];
}

// gathered activations, FRAGMENT-ORDERED: XpF[sb][kb][64 l][8 j]:
// lane l holds x[tok(sb*16 + (l&15))][kb*32 + (l>>4)*8 + j]. Pad slots -> 0.
__global__ void gather_k(const float* __restrict__ x, const int* __restrict__ ptok,
                         const int* __restrict__ ctrl, unsigned short* __restrict__ XpF) {
  const int sb = blockIdx.x * 4 + (threadIdx.x >> 6);   // slot-block, 4160 total
  const int l  = threadIdx.x & 63;
  const int slot = sb * 16 + (l & 15);
  bool valid = false;
#pragma unroll
  for (int e = 0; e < E_; ++e) {
    int off = ctrl[8 + e], c = ctrl[e];
    valid = valid || (slot >= off && slot < off + c);
  }
  const int tok = valid ? ptok[slot] : 0;
  const int g = l >> 4;
  unsigned short* dst = XpF + ((size_t)sb * 16) * 512 + l * 8;
#pragma unroll
  for (int kb = 0; kb < 16; ++kb) {
    us8 v = (us8){0, 0, 0, 0, 0, 0, 0, 0};
    if (valid) {
      const float* src = x + (size_t)tok * D_ + kb * 32 + g * 8;
      float4 a = *reinterpret_cast<const float4*>(src);
      float4 b = *reinterpret_cast<const float4*>(src + 4);
      v[0] = f2bf(a.x); v[1] = f2bf(a.y); v[2] = f2bf(a.z); v[3] = f2bf(a.w);
      v[4] = f2bf(b.x); v[5] = f2bf(b.y); v[6] = f2bf(b.z); v[7] = f2bf(b.w);
    }
    *reinterpret_cast<us8*>(dst + (size_t)kb * 512) = v;
  }
}

// M=64 tile: Xs 64KB + Hs 16KB = 80KB LDS -> 2 blocks/CU (4 waves/SIMD) for
// latency hiding. GEMM1: A(X) from LDS, B(W1F) direct global (L2-hot). H via
// XOR-swizzled Hs. GEMM2: A from Hs, B(W2B) direct global. All blocks on XCD c
// serve expert c (gid&7 both XCD-affine and expert index) -> weights L2-resident.
__global__ __launch_bounds__(512, 4) void ffn_k(
    const unsigned short* __restrict__ XpF,
    const unsigned short* __restrict__ W1F,   // [E][F/16][D/32][64][8]
    const unsigned short* __restrict__ W2B,   // [E][F/32][D/16][64][8]
    const int* __restrict__ ptok, const float* __restrict__ pgate,
    const int* __restrict__ ctrl, float* __restrict__ out) {
  const int gid = blockIdx.x;
  const int e = gid & 7;                      // XCD + expert affinity
  const int cnt = ctrl[e];
  const int tile0 = (gid >> 3) * M_TILE;
  if (tile0 >= cnt) return;
  const int slot0 = ctrl[8 + e] + tile0;      // 64-aligned (offsets 128-padded)
  const int sb0 = slot0 >> 4;

  __shared__ unsigned short Xs[32768];        // 64 KB: [sb_local*16+kb][lane*8]
  __shared__ unsigned short Hs[8192];         // 16 KB: [row][ch^(row&15)][8]

  const int tid = threadIdx.x;
  const int wid = tid >> 6, lane = tid & 63;
  const int lr = lane & 15, lg4 = lane >> 4;
  const int wm = wid >> 2, wn = wid & 3;      // 2m x 4n waves (both GEMMs)

  // ---- stage X panel once: 64 contiguous KB, linear DMA
  {
    const char* xsrc = (const char*)(XpF + (size_t)sb0 * 8192);
#pragma unroll
    for (int i = 0; i < 8; ++i) {
      const int o = (i * 512 + tid) * 16;
      gload16(xsrc + o, (char*)Xs + o);
    }
  }
  asm volatile("s_waitcnt vmcnt(0)" ::: "memory");
  __syncthreads();

  const unsigned short* w1e = W1F + (size_t)e * (F_ * D_);
  const unsigned short* W2e = W2B + (size_t)e * (F_ * D_);

  f32x4 acc[2][8];
#pragma unroll
  for (int i = 0; i < 2; ++i)
#pragma unroll
    for (int j = 0; j < 8; ++j) acc[i][j] = {0.f, 0.f, 0.f, 0.f};

  for (int jF = 0; jF < F_; jF += 128) {
    f32x4 hacc[2][2];
#pragma unroll
    for (int i = 0; i < 2; ++i)
#pragma unroll
      for (int j = 0; j < 2; ++j) hacc[i][j] = {0.f, 0.f, 0.f, 0.f};

    // wave covers f-frags fb = jF/16 + wn*2 + {0,1}; rows wm*32 + mi*16
    const unsigned short* w1b = w1e + ((size_t)((jF >> 4) + wn * 2) * 16) * 512 + lane * 8;

#pragma unroll
    for (int kb = 0; kb < 16; ++kb) {
      bf16x8 bw[2], af[2];
#pragma unroll
      for (int ni = 0; ni < 2; ++ni)
        bw[ni] = *reinterpret_cast<const bf16x8*>(w1b + ((size_t)ni * 16 + kb) * 512);
#pragma unroll
      for (int mi = 0; mi < 2; ++mi)
        af[mi] = *reinterpret_cast<const bf16x8*>(&Xs[((wm * 2 + mi) * 16 + kb) * 512 + lane * 8]);
#pragma unroll
      for (int mi = 0; mi < 2; ++mi)
#pragma unroll
        for (int ni = 0; ni < 2; ++ni)
          hacc[mi][ni] = __builtin_amdgcn_mfma_f32_16x16x32_bf16(af[mi], bw[ni], hacc[mi][ni], 0, 0, 0);
    }

    // ---- exact GELU -> Hs (bf16), 16B-chunk XOR swizzle (both sides)
#pragma unroll
    for (int mi = 0; mi < 2; ++mi)
#pragma unroll
      for (int ni = 0; ni < 2; ++ni)
#pragma unroll
        for (int r = 0; r < 4; ++r) {
          float v = hacc[mi][ni][r];
          float g = 0.5f * v * (1.f + erff(v * 0.70710678118654752f));
          const int row = wm * 32 + mi * 16 + lg4 * 4 + r;
          const int col = wn * 32 + ni * 16 + lr;
          const int ch = (col >> 3) ^ (row & 15);
          Hs[row * 128 + ch * 8 + (col & 7)] = f2bf(g);
        }
    __syncthreads();

    // ---- GEMM2: A from Hs (swizzled read), B from W2B global (L2-hot)
#pragma unroll
    for (int kb2 = 0; kb2 < 4; ++kb2) {
      const int fb = (jF >> 5) + kb2;
      bf16x8 bw2[8], ah[2];
#pragma unroll
      for (int ni = 0; ni < 8; ++ni)
        bw2[ni] = *reinterpret_cast<const bf16x8*>(W2e + ((size_t)fb * 32 + wn * 8 + ni) * 512 + lane * 8);
#pragma unroll
      for (int mi = 0; mi < 2; ++mi) {
        const int row = wm * 32 + mi * 16 + lr;
        const int ch = (kb2 * 4 + lg4) ^ (row & 15);
        ah[mi] = *reinterpret_cast<const bf16x8*>(&Hs[row * 128 + ch * 8]);
      }
#pragma unroll
      for (int mi = 0; mi < 2; ++mi)
#pragma unroll
        for (int ni = 0; ni < 8; ++ni)
          acc[mi][ni] = __builtin_amdgcn_mfma_f32_16x16x32_bf16(ah[mi], bw2[ni], acc[mi][ni], 0, 0, 0);
    }
    __syncthreads();
  }

  // ---- epilogue: gate from global, atomic-add (exactly 2 adds/elem -> deterministic)
  const int rowLim = cnt - tile0;
#pragma unroll
  for (int mi = 0; mi < 2; ++mi) {
#pragma unroll
    for (int r = 0; r < 4; ++r) {
      const int row = wm * 32 + mi * 16 + lg4 * 4 + r;
      if (row < rowLim) {
        const int tok = ptok[slot0 + row];
        const float gt = pgate[slot0 + row];
        float* orow = out + (size_t)tok * D_ + wn * 128 + lr;
#pragma unroll
        for (int ni = 0; ni < 8; ++ni)
          atomicAdd(orow + ni * 16, gt * acc[mi][ni][r]);
      }
    }
  }
}

extern "C" void kernel_launch(void* const* d_in, const int* in_sizes, int n_in,
                              void* d_out, int out_size, void* d_ws, size_t ws_size,
                              hipStream_t stream) {
  const float* x  = (const float*)d_in[0];
  const float* Wr = (const float*)d_in[1];
  const float* W1 = (const float*)d_in[2];
  const float* W2 = (const float*)d_in[3];
  float* out = (float*)d_out;

  char* w = (char*)d_ws;
  unsigned short* W1F = (unsigned short*)(w);                    // 16 MiB frag-ordered
  unsigned short* W2B = (unsigned short*)(w + 16777216);         // 16 MiB frag-ordered
  unsigned short* XpF = (unsigned short*)(w + 33554432);         // 65 MiB frag-ordered
  int*   ridx  = (int*)  (w + 101711872);
  float* rwgt  = (float*)(w + 101974016);
  int*   ptok  = (int*)  (w + 102236160);
  float* pgate = (float*)(w + 102502400);
  int*   ctrl  = (int*)  (w + 102768640);

  cvtW1_k<<<4096, 256, 0, stream>>>(W1, W1F);
  cvtW2_k<<<4096, 256, 0, stream>>>(W2, W2B);
  router_k<<<N_TOK / 4, 256, 0, stream>>>(x, Wr, ridx, rwgt);
  count_k<<<1, 1024, 0, stream>>>(ridx, ctrl);
  scatter_k<<<N_TOK * 2 / 512, 512, 0, stream>>>(ridx, rwgt, ctrl, ptok, pgate);
  gather_k<<<NSLOT_MAX / 16 / 4, 256, 0, stream>>>(x, ptok, ctrl, XpF);
  hipMemsetAsync(out, 0, (size_t)out_size * sizeof(float), stream);
  ffn_k<<<8192, 512, 0, stream>>>(XpF, W1F, W2B, ptok, pgate, ctrl, out);
}

// Round 8
// 742.774 us; speedup vs baseline: 1.6084x; 1.0163x over previous
//
#include <hip/hip_runtime.h>

#define N_TOK 32768
#define D_ 512
#define F_ 2048
#define E_ 8
#define M_TILE 64
#define NSLOT_MAX 66560   // 65536 + 8*128 padding, 128-aligned per expert

typedef __attribute__((ext_vector_type(8))) short bf16x8;
typedef __attribute__((ext_vector_type(8))) unsigned short us8;
typedef __attribute__((ext_vector_type(4))) float f32x4;

__device__ __forceinline__ unsigned short f2bf(float f) {
  union { float f; unsigned u; } v; v.f = f;
  unsigned r = v.u + 0x7fffu + ((v.u >> 16) & 1u);   // RNE; inputs finite
  return (unsigned short)(r >> 16);
}

__device__ __forceinline__ void gload16(const void* g, void* l) {
  __builtin_amdgcn_global_load_lds((const __attribute__((address_space(1))) void*)g,
                                   (__attribute__((address_space(3))) void*)l, 16, 0, 0);
}

// W1 [E][D][F] f32 -> fragment-ordered bf16 W1F [E][F/16 fb][D/32 kb][64 l][8 j]:
// lane l holds W1[e][kb*32+(l>>4)*8+j][fb*16+(l&15)]
__global__ void cvtW1_k(const float* __restrict__ W1, unsigned short* __restrict__ W1F) {
  const int gw = blockIdx.x * 4 + (threadIdx.x >> 6);   // 16384 waves
  const int l  = threadIdx.x & 63;
  const int kb = gw & 15;
  const int fb = (gw >> 4) & 127;
  const int e  = gw >> 11;
  const int f  = fb * 16 + (l & 15);
  const int k0 = kb * 32 + (l >> 4) * 8;
  const float* src = W1 + ((size_t)e * D_ + k0) * F_ + f;
  us8 v;
#pragma unroll
  for (int j = 0; j < 8; ++j) v[j] = f2bf(src[(size_t)j * F_]);
  *reinterpret_cast<us8*>(W1F + ((size_t)gw * 64 + l) * 8) = v;
}

// W2 [E][F][D] f32 -> fragment-ordered bf16:
// dest[((e*64+fb)*32+db)*512 + l*8 + j] = bf16(W2[e][fb*32+(l>>4)*8+j][db*16+(l&15)])
__global__ void cvtW2_k(const float* __restrict__ W2, unsigned short* __restrict__ W2B) {
  const int gid = blockIdx.x * 256 + threadIdx.x;    // 1,048,576 total
  const int l  = gid & 63;
  const int db = (gid >> 6) & 31;
  const int fb = (gid >> 11) & 63;
  const int e  = gid >> 17;
  const int d  = db * 16 + (l & 15);
  const int f0 = fb * 32 + (l >> 4) * 8;
  const float* src = W2 + ((size_t)e * F_ + f0) * D_ + d;
  us8 v;
#pragma unroll
  for (int j = 0; j < 8; ++j) v[j] = f2bf(src[(size_t)j * D_]);
  *reinterpret_cast<us8*>(W2B + (size_t)gid * 8) = v;
}

// one wave per token: logits = x_row @ Wr, softmax fp32, top-2. NO atomics.
__global__ void router_k(const float* __restrict__ x, const float* __restrict__ Wr,
                         int* __restrict__ ridx, float* __restrict__ rw) {
  const int wid = threadIdx.x >> 6, lane = threadIdx.x & 63;
  const int t = blockIdx.x * 4 + wid;
  const float* xr = x + (size_t)t * D_ + lane * 8;
  const float4 xa = *reinterpret_cast<const float4*>(xr);
  const float4 xb = *reinterpret_cast<const float4*>(xr + 4);
  float xv[8] = {xa.x, xa.y, xa.z, xa.w, xb.x, xb.y, xb.z, xb.w};
  float lg[8] = {0, 0, 0, 0, 0, 0, 0, 0};
#pragma unroll
  for (int j = 0; j < 8; ++j) {
    const float* wr = Wr + (size_t)(lane * 8 + j) * E_;
    float4 w0 = *reinterpret_cast<const float4*>(wr);
    float4 w1 = *reinterpret_cast<const float4*>(wr + 4);
    lg[0] += xv[j] * w0.x; lg[1] += xv[j] * w0.y; lg[2] += xv[j] * w0.z; lg[3] += xv[j] * w0.w;
    lg[4] += xv[j] * w1.x; lg[5] += xv[j] * w1.y; lg[6] += xv[j] * w1.z; lg[7] += xv[j] * w1.w;
  }
#pragma unroll
  for (int off = 32; off; off >>= 1) {
#pragma unroll
    for (int q = 0; q < 8; ++q) lg[q] += __shfl_xor(lg[q], off);
  }
  if (lane == 0) {
    float m = lg[0];
#pragma unroll
    for (int q = 1; q < 8; ++q) m = fmaxf(m, lg[q]);
    float p[8]; float s = 0.f;
#pragma unroll
    for (int q = 0; q < 8; ++q) { p[q] = expf(lg[q] - m); s += p[q]; }
    float inv = 1.f / s;
    int e1 = 0;
#pragma unroll
    for (int q = 1; q < 8; ++q) if (p[q] > p[e1]) e1 = q;
    int e2 = (e1 == 0) ? 1 : 0;
#pragma unroll
    for (int q = 0; q < 8; ++q) { if (q == e1) continue; if (p[q] > p[e2]) e2 = q; }
    ridx[2 * t] = e1; ridx[2 * t + 1] = e2;
    rw[2 * t] = p[e1] * inv; rw[2 * t + 1] = p[e2] * inv;
  }
}

// single block: counts, 128-padded offsets, zero cursors
__global__ void count_k(const int* __restrict__ ridx, int* __restrict__ ctrl) {
  __shared__ int h[E_];
  const int tid = threadIdx.x;   // 1024
  if (tid < E_) h[tid] = 0;
  __syncthreads();
  int c0=0,c1=0,c2=0,c3=0,c4=0,c5=0,c6=0,c7=0;
  for (int i = tid; i < 2 * N_TOK; i += 1024) {
    int v = ridx[i];
    c0 += (v == 0); c1 += (v == 1); c2 += (v == 2); c3 += (v == 3);
    c4 += (v == 4); c5 += (v == 5); c6 += (v == 6); c7 += (v == 7);
  }
  atomicAdd(&h[0], c0); atomicAdd(&h[1], c1); atomicAdd(&h[2], c2); atomicAdd(&h[3], c3);
  atomicAdd(&h[4], c4); atomicAdd(&h[5], c5); atomicAdd(&h[6], c6); atomicAdd(&h[7], c7);
  __syncthreads();
  if (tid == 0) {
    int a = 0;
    for (int e = 0; e < E_; ++e) {
      ctrl[e] = h[e];
      ctrl[8 + e] = a;
      a += (h[e] + 127) & ~127;
      ctrl[16 + e] = 0;
    }
    ctrl[24] = a;
  }
}

// per-block LDS ranks + 8 global atomics per block
__global__ void scatter_k(const int* __restrict__ ridx, const float* __restrict__ rw,
                          int* __restrict__ ctrl, int* __restrict__ ptok,
                          float* __restrict__ pgate) {
  __shared__ int h[E_], base[E_];
  const int tid = threadIdx.x;                 // 512
  const int g = blockIdx.x * 512 + tid;        // entry id
  if (tid < E_) h[tid] = 0;
  __syncthreads();
  const int e = ridx[g];
  const int r = atomicAdd(&h[e], 1);           // LDS atomic
  __syncthreads();
  if (tid < E_) base[tid] = atomicAdd(&ctrl[16 + tid], h[tid]);
  __syncthreads();
  const int pos = ctrl[8 + e] + base[e] + r;
  ptok[pos] = g >> 1;
  pgate[pos] = rw[g];
}

// gathered activations, FRAGMENT-ORDERED: XpF[sb][kb][64 l][8 j]:
// lane l holds x[tok(sb*16 + (l&15))][kb*32 + (l>>4)*8 + j]. Pad slots -> 0.
__global__ void gather_k(const float* __restrict__ x, const int* __restrict__ ptok,
                         const int* __restrict__ ctrl, unsigned short* __restrict__ XpF) {
  const int sb = blockIdx.x * 4 + (threadIdx.x >> 6);   // slot-block, 4160 total
  const int l  = threadIdx.x & 63;
  const int slot = sb * 16 + (l & 15);
  bool valid = false;
#pragma unroll
  for (int e = 0; e < E_; ++e) {
    int off = ctrl[8 + e], c = ctrl[e];
    valid = valid || (slot >= off && slot < off + c);
  }
  const int tok = valid ? ptok[slot] : 0;
  const int g = l >> 4;
  unsigned short* dst = XpF + ((size_t)sb * 16) * 512 + l * 8;
#pragma unroll
  for (int kb = 0; kb < 16; ++kb) {
    us8 v = (us8){0, 0, 0, 0, 0, 0, 0, 0};
    if (valid) {
      const float* src = x + (size_t)tok * D_ + kb * 32 + g * 8;
      float4 a = *reinterpret_cast<const float4*>(src);
      float4 b = *reinterpret_cast<const float4*>(src + 4);
      v[0] = f2bf(a.x); v[1] = f2bf(a.y); v[2] = f2bf(a.z); v[3] = f2bf(a.w);
      v[4] = f2bf(b.x); v[5] = f2bf(b.y); v[6] = f2bf(b.z); v[7] = f2bf(b.w);
    }
    *reinterpret_cast<us8*>(dst + (size_t)kb * 512) = v;
  }
}

// M=64, 1m x 8n wave layout: every weight fragment read EXACTLY ONCE per block
// (no wm duplication -> halves per-XCD L2 traffic vs R7). Each wave owns all 64
// rows x its n-slice: GEMM1 wave = 1 f-frag (16 f), GEMM2 wave = 4 d-frags (64 d).
// Xs 64KB + Hs 16KB = 80KB -> 2 blocks/CU. e = gid&7 XCD+expert affinity.
__global__ __launch_bounds__(512, 4) void ffn_k(
    const unsigned short* __restrict__ XpF,
    const unsigned short* __restrict__ W1F,   // [E][F/16][D/32][64][8]
    const unsigned short* __restrict__ W2B,   // [E][F/32][D/16][64][8]
    const int* __restrict__ ptok, const float* __restrict__ pgate,
    const int* __restrict__ ctrl, float* __restrict__ out) {
  const int gid = blockIdx.x;
  const int e = gid & 7;                      // XCD + expert affinity
  const int cnt = ctrl[e];
  const int tile0 = (gid >> 3) * M_TILE;
  if (tile0 >= cnt) return;
  const int slot0 = ctrl[8 + e] + tile0;      // 64-aligned (offsets 128-padded)
  const int sb0 = slot0 >> 4;

  __shared__ unsigned short Xs[32768];        // 64 KB: [sb_local*16+kb][lane*8]
  __shared__ unsigned short Hs[8192];         // 16 KB: [row][ch^(row&15)][8]

  const int tid = threadIdx.x;
  const int wn = tid >> 6, lane = tid & 63;   // 8 waves = 8 n-slices
  const int lr = lane & 15, lg4 = lane >> 4;

  // ---- stage X panel once: 64 contiguous KB, linear DMA
  {
    const char* xsrc = (const char*)(XpF + (size_t)sb0 * 8192);
#pragma unroll
    for (int i = 0; i < 8; ++i) {
      const int o = (i * 512 + tid) * 16;
      gload16(xsrc + o, (char*)Xs + o);
    }
  }
  asm volatile("s_waitcnt vmcnt(0)" ::: "memory");
  __syncthreads();

  const unsigned short* w1e = W1F + (size_t)e * (F_ * D_);
  const unsigned short* W2e = W2B + (size_t)e * (F_ * D_);

  f32x4 acc[4][4];                            // [mi rows][ni d-frags]
#pragma unroll
  for (int i = 0; i < 4; ++i)
#pragma unroll
    for (int j = 0; j < 4; ++j) acc[i][j] = {0.f, 0.f, 0.f, 0.f};

  for (int jF = 0; jF < F_; jF += 128) {
    f32x4 hacc[4];                            // rows mi*16, single f-frag
#pragma unroll
    for (int i = 0; i < 4; ++i) hacc[i] = {0.f, 0.f, 0.f, 0.f};

    // wave's f-frag: fb1 = jF/16 + wn
    const unsigned short* w1b = w1e + ((size_t)((jF >> 4) + wn) * 16) * 512 + lane * 8;

#pragma unroll
    for (int kb = 0; kb < 16; ++kb) {
      bf16x8 bw = *reinterpret_cast<const bf16x8*>(w1b + (size_t)kb * 512);
      bf16x8 af[4];
#pragma unroll
      for (int mi = 0; mi < 4; ++mi)
        af[mi] = *reinterpret_cast<const bf16x8*>(&Xs[(mi * 16 + kb) * 512 + lane * 8]);
#pragma unroll
      for (int mi = 0; mi < 4; ++mi)
        hacc[mi] = __builtin_amdgcn_mfma_f32_16x16x32_bf16(af[mi], bw, hacc[mi], 0, 0, 0);
    }

    // ---- exact GELU -> Hs (bf16), 16B-chunk XOR swizzle (both sides)
#pragma unroll
    for (int mi = 0; mi < 4; ++mi)
#pragma unroll
      for (int r = 0; r < 4; ++r) {
        float v = hacc[mi][r];
        float g = 0.5f * v * (1.f + erff(v * 0.70710678118654752f));
        const int row = mi * 16 + lg4 * 4 + r;
        const int col = wn * 16 + lr;
        const int ch = (col >> 3) ^ (row & 15);
        Hs[row * 128 + ch * 8 + (col & 7)] = f2bf(g);
      }
    __syncthreads();

    // ---- GEMM2: A from Hs (swizzled read), B from W2B global, d-frags wn*4+ni
#pragma unroll
    for (int kb2 = 0; kb2 < 4; ++kb2) {
      const int fb = (jF >> 5) + kb2;
      bf16x8 bw2[4], ah[4];
#pragma unroll
      for (int ni = 0; ni < 4; ++ni)
        bw2[ni] = *reinterpret_cast<const bf16x8*>(W2e + ((size_t)fb * 32 + wn * 4 + ni) * 512 + lane * 8);
#pragma unroll
      for (int mi = 0; mi < 4; ++mi) {
        const int row = mi * 16 + lr;
        const int ch = (kb2 * 4 + lg4) ^ (row & 15);
        ah[mi] = *reinterpret_cast<const bf16x8*>(&Hs[row * 128 + ch * 8]);
      }
#pragma unroll
      for (int mi = 0; mi < 4; ++mi)
#pragma unroll
        for (int ni = 0; ni < 4; ++ni)
          acc[mi][ni] = __builtin_amdgcn_mfma_f32_16x16x32_bf16(ah[mi], bw2[ni], acc[mi][ni], 0, 0, 0);
    }
    __syncthreads();
  }

  // ---- epilogue: gate from global, atomic-add (exactly 2 adds/elem -> deterministic)
  const int rowLim = cnt - tile0;
#pragma unroll
  for (int mi = 0; mi < 4; ++mi) {
#pragma unroll
    for (int r = 0; r < 4; ++r) {
      const int row = mi * 16 + lg4 * 4 + r;
      if (row < rowLim) {
        const int tok = ptok[slot0 + row];
        const float gt = pgate[slot0 + row];
        float* orow = out + (size_t)tok * D_ + wn * 64 + lr;
#pragma unroll
        for (int ni = 0; ni < 4; ++ni)
          atomicAdd(orow + ni * 16, gt * acc[mi][ni][r]);
      }
    }
  }
}

extern "C" void kernel_launch(void* const* d_in, const int* in_sizes, int n_in,
                              void* d_out, int out_size, void* d_ws, size_t ws_size,
                              hipStream_t stream) {
  const float* x  = (const float*)d_in[0];
  const float* Wr = (const float*)d_in[1];
  const float* W1 = (const float*)d_in[2];
  const float* W2 = (const float*)d_in[3];
  float* out = (float*)d_out;

  char* w = (char*)d_ws;
  unsigned short* W1F = (unsigned short*)(w);                    // 16 MiB frag-ordered
  unsigned short* W2B = (unsigned short*)(w + 16777216);         // 16 MiB frag-ordered
  unsigned short* XpF = (unsigned short*)(w + 33554432);         // 65 MiB frag-ordered
  int*   ridx  = (int*)  (w + 101711872);
  float* rwgt  = (float*)(w + 101974016);
  int*   ptok  = (int*)  (w + 102236160);
  float* pgate = (float*)(w + 102502400);
  int*   ctrl  = (int*)  (w + 102768640);

  cvtW1_k<<<4096, 256, 0, stream>>>(W1, W1F);
  cvtW2_k<<<4096, 256, 0, stream>>>(W2, W2B);
  router_k<<<N_TOK / 4, 256, 0, stream>>>(x, Wr, ridx, rwgt);
  count_k<<<1, 1024, 0, stream>>>(ridx, ctrl);
  scatter_k<<<N_TOK * 2 / 512, 512, 0, stream>>>(ridx, rwgt, ctrl, ptok, pgate);
  gather_k<<<NSLOT_MAX / 16 / 4, 256, 0, stream>>>(x, ptok, ctrl, XpF);
  hipMemsetAsync(out, 0, (size_t)out_size * sizeof(float), stream);
  ffn_k<<<8192, 512, 0, stream>>>(XpF, W1F, W2B, ptok, pgate, ctrl, out);
}

// Round 9
// 686.612 us; speedup vs baseline: 1.7400x; 1.0818x over previous
//
#include <hip/hip_runtime.h>

#define N_TOK 32768
#define D_ 512
#define F_ 2048
#define E_ 8
#define M_TILE 64
#define NSLOT_MAX 66560   // 65536 + 8*128 padding, 128-aligned per expert

typedef __attribute__((ext_vector_type(8))) short bf16x8;
typedef __attribute__((ext_vector_type(8))) unsigned short us8;
typedef __attribute__((ext_vector_type(4))) float f32x4;

__device__ __forceinline__ unsigned short f2bf(float f) {
  union { float f; unsigned u; } v; v.f = f;
  unsigned r = v.u + 0x7fffu + ((v.u >> 16) & 1u);   // RNE; inputs finite
  return (unsigned short)(r >> 16);
}

__device__ __forceinline__ void gload16(const void* g, void* l) {
  __builtin_amdgcn_global_load_lds((const __attribute__((address_space(1))) void*)g,
                                   (__attribute__((address_space(3))) void*)l, 16, 0, 0);
}

// W1 [E][D][F] f32 -> fragment-ordered bf16 W1F [E][F/16 fb][D/32 kb][64 l][8 j]:
// lane l holds W1[e][kb*32+(l>>4)*8+j][fb*16+(l&15)]
__global__ void cvtW1_k(const float* __restrict__ W1, unsigned short* __restrict__ W1F) {
  const int gw = blockIdx.x * 4 + (threadIdx.x >> 6);   // 16384 waves
  const int l  = threadIdx.x & 63;
  const int kb = gw & 15;
  const int fb = (gw >> 4) & 127;
  const int e  = gw >> 11;
  const int f  = fb * 16 + (l & 15);
  const int k0 = kb * 32 + (l >> 4) * 8;
  const float* src = W1 + ((size_t)e * D_ + k0) * F_ + f;
  us8 v;
#pragma unroll
  for (int j = 0; j < 8; ++j) v[j] = f2bf(src[(size_t)j * F_]);
  *reinterpret_cast<us8*>(W1F + ((size_t)gw * 64 + l) * 8) = v;
}

// W2 [E][F][D] f32 -> fragment-ordered bf16:
// dest[((e*64+fb)*32+db)*512 + l*8 + j] = bf16(W2[e][fb*32+(l>>4)*8+j][db*16+(l&15)])
__global__ void cvtW2_k(const float* __restrict__ W2, unsigned short* __restrict__ W2B) {
  const int gid = blockIdx.x * 256 + threadIdx.x;    // 1,048,576 total
  const int l  = gid & 63;
  const int db = (gid >> 6) & 31;
  const int fb = (gid >> 11) & 63;
  const int e  = gid >> 17;
  const int d  = db * 16 + (l & 15);
  const int f0 = fb * 32 + (l >> 4) * 8;
  const float* src = W2 + ((size_t)e * F_ + f0) * D_ + d;
  us8 v;
#pragma unroll
  for (int j = 0; j < 8; ++j) v[j] = f2bf(src[(size_t)j * D_]);
  *reinterpret_cast<us8*>(W2B + (size_t)gid * 8) = v;
}

// one wave per token: logits = x_row @ Wr, softmax fp32, top-2. NO atomics.
__global__ void router_k(const float* __restrict__ x, const float* __restrict__ Wr,
                         int* __restrict__ ridx, float* __restrict__ rw) {
  const int wid = threadIdx.x >> 6, lane = threadIdx.x & 63;
  const int t = blockIdx.x * 4 + wid;
  const float* xr = x + (size_t)t * D_ + lane * 8;
  const float4 xa = *reinterpret_cast<const float4*>(xr);
  const float4 xb = *reinterpret_cast<const float4*>(xr + 4);
  float xv[8] = {xa.x, xa.y, xa.z, xa.w, xb.x, xb.y, xb.z, xb.w};
  float lg[8] = {0, 0, 0, 0, 0, 0, 0, 0};
#pragma unroll
  for (int j = 0; j < 8; ++j) {
    const float* wr = Wr + (size_t)(lane * 8 + j) * E_;
    float4 w0 = *reinterpret_cast<const float4*>(wr);
    float4 w1 = *reinterpret_cast<const float4*>(wr + 4);
    lg[0] += xv[j] * w0.x; lg[1] += xv[j] * w0.y; lg[2] += xv[j] * w0.z; lg[3] += xv[j] * w0.w;
    lg[4] += xv[j] * w1.x; lg[5] += xv[j] * w1.y; lg[6] += xv[j] * w1.z; lg[7] += xv[j] * w1.w;
  }
#pragma unroll
  for (int off = 32; off; off >>= 1) {
#pragma unroll
    for (int q = 0; q < 8; ++q) lg[q] += __shfl_xor(lg[q], off);
  }
  if (lane == 0) {
    float m = lg[0];
#pragma unroll
    for (int q = 1; q < 8; ++q) m = fmaxf(m, lg[q]);
    float p[8]; float s = 0.f;
#pragma unroll
    for (int q = 0; q < 8; ++q) { p[q] = expf(lg[q] - m); s += p[q]; }
    float inv = 1.f / s;
    int e1 = 0;
#pragma unroll
    for (int q = 1; q < 8; ++q) if (p[q] > p[e1]) e1 = q;
    int e2 = (e1 == 0) ? 1 : 0;
#pragma unroll
    for (int q = 0; q < 8; ++q) { if (q == e1) continue; if (p[q] > p[e2]) e2 = q; }
    ridx[2 * t] = e1; ridx[2 * t + 1] = e2;
    rw[2 * t] = p[e1] * inv; rw[2 * t + 1] = p[e2] * inv;
  }
}

// single block: counts, 128-padded offsets, zero cursors
__global__ void count_k(const int* __restrict__ ridx, int* __restrict__ ctrl) {
  __shared__ int h[E_];
  const int tid = threadIdx.x;   // 1024
  if (tid < E_) h[tid] = 0;
  __syncthreads();
  int c0=0,c1=0,c2=0,c3=0,c4=0,c5=0,c6=0,c7=0;
  for (int i = tid; i < 2 * N_TOK; i += 1024) {
    int v = ridx[i];
    c0 += (v == 0); c1 += (v == 1); c2 += (v == 2); c3 += (v == 3);
    c4 += (v == 4); c5 += (v == 5); c6 += (v == 6); c7 += (v == 7);
  }
  atomicAdd(&h[0], c0); atomicAdd(&h[1], c1); atomicAdd(&h[2], c2); atomicAdd(&h[3], c3);
  atomicAdd(&h[4], c4); atomicAdd(&h[5], c5); atomicAdd(&h[6], c6); atomicAdd(&h[7], c7);
  __syncthreads();
  if (tid == 0) {
    int a = 0;
    for (int e = 0; e < E_; ++e) {
      ctrl[e] = h[e];
      ctrl[8 + e] = a;
      a += (h[e] + 127) & ~127;
      ctrl[16 + e] = 0;
    }
    ctrl[24] = a;
  }
}

// per-block LDS ranks + 8 global atomics per block
__global__ void scatter_k(const int* __restrict__ ridx, const float* __restrict__ rw,
                          int* __restrict__ ctrl, int* __restrict__ ptok,
                          float* __restrict__ pgate) {
  __shared__ int h[E_], base[E_];
  const int tid = threadIdx.x;                 // 512
  const int g = blockIdx.x * 512 + tid;        // entry id
  if (tid < E_) h[tid] = 0;
  __syncthreads();
  const int e = ridx[g];
  const int r = atomicAdd(&h[e], 1);           // LDS atomic
  __syncthreads();
  if (tid < E_) base[tid] = atomicAdd(&ctrl[16 + tid], h[tid]);
  __syncthreads();
  const int pos = ctrl[8 + e] + base[e] + r;
  ptok[pos] = g >> 1;
  pgate[pos] = rw[g];
}

// gathered activations, FRAGMENT-ORDERED: XpF[sb][kb][64 l][8 j]:
// lane l holds x[tok(sb*16 + (l&15))][kb*32 + (l>>4)*8 + j]. Pad slots -> 0.
__global__ void gather_k(const float* __restrict__ x, const int* __restrict__ ptok,
                         const int* __restrict__ ctrl, unsigned short* __restrict__ XpF) {
  const int sb = blockIdx.x * 4 + (threadIdx.x >> 6);   // slot-block, 4160 total
  const int l  = threadIdx.x & 63;
  const int slot = sb * 16 + (l & 15);
  bool valid = false;
#pragma unroll
  for (int e = 0; e < E_; ++e) {
    int off = ctrl[8 + e], c = ctrl[e];
    valid = valid || (slot >= off && slot < off + c);
  }
  const int tok = valid ? ptok[slot] : 0;
  const int g = l >> 4;
  unsigned short* dst = XpF + ((size_t)sb * 16) * 512 + l * 8;
#pragma unroll
  for (int kb = 0; kb < 16; ++kb) {
    us8 v = (us8){0, 0, 0, 0, 0, 0, 0, 0};
    if (valid) {
      const float* src = x + (size_t)tok * D_ + kb * 32 + g * 8;
      float4 a = *reinterpret_cast<const float4*>(src);
      float4 b = *reinterpret_cast<const float4*>(src + 4);
      v[0] = f2bf(a.x); v[1] = f2bf(a.y); v[2] = f2bf(a.z); v[3] = f2bf(a.w);
      v[4] = f2bf(b.x); v[5] = f2bf(b.y); v[6] = f2bf(b.z); v[7] = f2bf(b.w);
    }
    *reinterpret_cast<us8*>(dst + (size_t)kb * 512) = v;
  }
}

// M=64, 1m x 8n wave layout (weight frags read once per block). Explicit
// double-buffered register prefetch of weight fragments (forces the compiler
// to keep 4 L2 loads in flight ahead of the consuming MFMAs); GEMM2 kb2=0
// fragments issued BEFORE the GELU phase so L2 latency hides under VALU+barrier.
// Fast sigmoid-form GELU (|err| vs exact erf-GELU ~3e-3 on H, ~1e-3 on out).
__global__ __launch_bounds__(512, 4) void ffn_k(
    const unsigned short* __restrict__ XpF,
    const unsigned short* __restrict__ W1F,   // [E][F/16][D/32][64][8]
    const unsigned short* __restrict__ W2B,   // [E][F/32][D/16][64][8]
    const int* __restrict__ ptok, const float* __restrict__ pgate,
    const int* __restrict__ ctrl, float* __restrict__ out) {
  const int gid = blockIdx.x;
  const int e = gid & 7;                      // XCD + expert affinity
  const int cnt = ctrl[e];
  const int tile0 = (gid >> 3) * M_TILE;
  if (tile0 >= cnt) return;
  const int slot0 = ctrl[8 + e] + tile0;      // 64-aligned (offsets 128-padded)
  const int sb0 = slot0 >> 4;

  __shared__ unsigned short Xs[32768];        // 64 KB: [sb_local*16+kb][lane*8]
  __shared__ unsigned short Hs[8192];         // 16 KB: [row][ch^(row&15)][8]

  const int tid = threadIdx.x;
  const int wn = tid >> 6, lane = tid & 63;   // 8 waves = 8 n-slices
  const int lr = lane & 15, lg4 = lane >> 4;

  // ---- stage X panel once: 64 contiguous KB, linear DMA
  {
    const char* xsrc = (const char*)(XpF + (size_t)sb0 * 8192);
#pragma unroll
    for (int i = 0; i < 8; ++i) {
      const int o = (i * 512 + tid) * 16;
      gload16(xsrc + o, (char*)Xs + o);
    }
  }
  asm volatile("s_waitcnt vmcnt(0)" ::: "memory");
  __syncthreads();

  const unsigned short* w1e = W1F + (size_t)e * (F_ * D_);
  const unsigned short* W2e = W2B + (size_t)e * (F_ * D_);

  f32x4 acc[4][4];                            // [mi rows][ni d-frags]
#pragma unroll
  for (int i = 0; i < 4; ++i)
#pragma unroll
    for (int j = 0; j < 4; ++j) acc[i][j] = {0.f, 0.f, 0.f, 0.f};

  for (int jF = 0; jF < F_; jF += 128) {
    f32x4 hacc[4];
#pragma unroll
    for (int i = 0; i < 4; ++i) hacc[i] = {0.f, 0.f, 0.f, 0.f};

    // wave's f-frag: fb1 = jF/16 + wn; kb stride 512 ushorts
    const unsigned short* w1b = w1e + ((size_t)((jF >> 4) + wn) * 16) * 512 + lane * 8;
    // GEMM2 base: frag (fb*32 + wn*4 + ni), fb = jF/32 + kb2; kb2 stride 16384
    const unsigned short* w2b = W2e + ((size_t)((jF >> 5) * 32 + wn * 4)) * 512 + lane * 8;

    // ---- GEMM1: explicit 2-deep group prefetch (groups of 4 kb)
    bf16x8 bw[2][4];
#pragma unroll
    for (int i = 0; i < 4; ++i)
      bw[0][i] = *reinterpret_cast<const bf16x8*>(w1b + (size_t)i * 512);
#pragma unroll
    for (int g = 0; g < 4; ++g) {
      const int cur = g & 1, nxt = cur ^ 1;
      if (g < 3) {
#pragma unroll
        for (int i = 0; i < 4; ++i)
          bw[nxt][i] = *reinterpret_cast<const bf16x8*>(w1b + (size_t)((g + 1) * 4 + i) * 512);
      }
#pragma unroll
      for (int i = 0; i < 4; ++i) {
        const int kb = g * 4 + i;
#pragma unroll
        for (int mi = 0; mi < 4; ++mi) {
          bf16x8 af = *reinterpret_cast<const bf16x8*>(&Xs[(mi * 16 + kb) * 512 + lane * 8]);
          hacc[mi] = __builtin_amdgcn_mfma_f32_16x16x32_bf16(af, bw[cur][i], hacc[mi], 0, 0, 0);
        }
      }
    }

    // ---- issue GEMM2 kb2=0 weight loads NOW (in flight during GELU + barrier)
    bf16x8 b2[2][4];
#pragma unroll
    for (int i = 0; i < 4; ++i)
      b2[0][i] = *reinterpret_cast<const bf16x8*>(w2b + (size_t)i * 512);

    // ---- fast GELU -> Hs (bf16), 16B-chunk XOR swizzle (both sides)
#pragma unroll
    for (int mi = 0; mi < 4; ++mi)
#pragma unroll
      for (int r = 0; r < 4; ++r) {
        float v = hacc[mi][r];
        float u = v * v;
        float wv = v * fmaf(0.044715f, u, 1.0f);
        float z = __expf(-1.5957691216057308f * wv);
        float g = v * __frcp_rn(1.0f + z);            // v * sigmoid(2t)
        const int row = mi * 16 + lg4 * 4 + r;
        const int col = wn * 16 + lr;
        const int ch = (col >> 3) ^ (row & 15);
        Hs[row * 128 + ch * 8 + (col & 7)] = f2bf(g);
      }
    __syncthreads();

    // ---- GEMM2: A from Hs (swizzled), B prefetched 1 kb2 ahead
#pragma unroll
    for (int kb2 = 0; kb2 < 4; ++kb2) {
      const int cur = kb2 & 1, nxt = cur ^ 1;
      if (kb2 < 3) {
#pragma unroll
        for (int i = 0; i < 4; ++i)
          b2[nxt][i] = *reinterpret_cast<const bf16x8*>(w2b + (size_t)((kb2 + 1) * 16384 + i * 512));
      }
      bf16x8 ah[4];
#pragma unroll
      for (int mi = 0; mi < 4; ++mi) {
        const int row = mi * 16 + lr;
        const int ch = (kb2 * 4 + lg4) ^ (row & 15);
        ah[mi] = *reinterpret_cast<const bf16x8*>(&Hs[row * 128 + ch * 8]);
      }
#pragma unroll
      for (int mi = 0; mi < 4; ++mi)
#pragma unroll
        for (int ni = 0; ni < 4; ++ni)
          acc[mi][ni] = __builtin_amdgcn_mfma_f32_16x16x32_bf16(ah[mi], b2[cur][ni], acc[mi][ni], 0, 0, 0);
    }
    __syncthreads();
  }

  // ---- epilogue: gate from global, atomic-add (exactly 2 adds/elem -> deterministic)
  const int rowLim = cnt - tile0;
#pragma unroll
  for (int mi = 0; mi < 4; ++mi) {
#pragma unroll
    for (int r = 0; r < 4; ++r) {
      const int row = mi * 16 + lg4 * 4 + r;
      if (row < rowLim) {
        const int tok = ptok[slot0 + row];
        const float gt = pgate[slot0 + row];
        float* orow = out + (size_t)tok * D_ + wn * 64 + lr;
#pragma unroll
        for (int ni = 0; ni < 4; ++ni)
          atomicAdd(orow + ni * 16, gt * acc[mi][ni][r]);
      }
    }
  }
}

extern "C" void kernel_launch(void* const* d_in, const int* in_sizes, int n_in,
                              void* d_out, int out_size, void* d_ws, size_t ws_size,
                              hipStream_t stream) {
  const float* x  = (const float*)d_in[0];
  const float* Wr = (const float*)d_in[1];
  const float* W1 = (const float*)d_in[2];
  const float* W2 = (const float*)d_in[3];
  float* out = (float*)d_out;

  char* w = (char*)d_ws;
  unsigned short* W1F = (unsigned short*)(w);                    // 16 MiB frag-ordered
  unsigned short* W2B = (unsigned short*)(w + 16777216);         // 16 MiB frag-ordered
  unsigned short* XpF = (unsigned short*)(w + 33554432);         // 65 MiB frag-ordered
  int*   ridx  = (int*)  (w + 101711872);
  float* rwgt  = (float*)(w + 101974016);
  int*   ptok  = (int*)  (w + 102236160);
  float* pgate = (float*)(w + 102502400);
  int*   ctrl  = (int*)  (w + 102768640);

  cvtW1_k<<<4096, 256, 0, stream>>>(W1, W1F);
  cvtW2_k<<<4096, 256, 0, stream>>>(W2, W2B);
  router_k<<<N_TOK / 4, 256, 0, stream>>>(x, Wr, ridx, rwgt);
  count_k<<<1, 1024, 0, stream>>>(ridx, ctrl);
  scatter_k<<<N_TOK * 2 / 512, 512, 0, stream>>>(ridx, rwgt, ctrl, ptok, pgate);
  gather_k<<<NSLOT_MAX / 16 / 4, 256, 0, stream>>>(x, ptok, ctrl, XpF);
  hipMemsetAsync(out, 0, (size_t)out_size * sizeof(float), stream);
  ffn_k<<<8192, 512, 0, stream>>>(XpF, W1F, W2B, ptok, pgate, ctrl, out);
}

// Round 10
// 607.156 us; speedup vs baseline: 1.9677x; 1.1309x over previous
//
#include <hip/hip_runtime.h>

#define N_TOK 32768
#define D_ 512
#define F_ 2048
#define E_ 8
#define M_TILE 64
#define NSLOT_MAX 66560   // 65536 + 8*128 padding, 128-aligned per expert

typedef __attribute__((ext_vector_type(8))) short bf16x8;
typedef __attribute__((ext_vector_type(8))) unsigned short us8;
typedef __attribute__((ext_vector_type(4))) float f32x4;

__device__ __forceinline__ unsigned short f2bf(float f) {
  union { float f; unsigned u; } v; v.f = f;
  unsigned r = v.u + 0x7fffu + ((v.u >> 16) & 1u);   // RNE; inputs finite
  return (unsigned short)(r >> 16);
}

__device__ __forceinline__ void gload16(const void* g, void* l) {
  __builtin_amdgcn_global_load_lds((const __attribute__((address_space(1))) void*)g,
                                   (__attribute__((address_space(3))) void*)l, 16, 0, 0);
}

// lgkm-only barrier: LDS ordering without draining vmcnt (in-flight global->reg
// prefetches ride across). "memory" clobber pins all memory ops on both sides.
__device__ __forceinline__ void lbar() {
  asm volatile("s_waitcnt lgkmcnt(0)" ::: "memory");
  __builtin_amdgcn_s_barrier();
}

// W1 [E][D][F] f32 -> fragment-ordered bf16 W1F [E][F/16 fb][D/32 kb][64 l][8 j]:
// lane l holds W1[e][kb*32+(l>>4)*8+j][fb*16+(l&15)]
__global__ void cvtW1_k(const float* __restrict__ W1, unsigned short* __restrict__ W1F) {
  const int gw = blockIdx.x * 4 + (threadIdx.x >> 6);   // 16384 waves
  const int l  = threadIdx.x & 63;
  const int kb = gw & 15;
  const int fb = (gw >> 4) & 127;
  const int e  = gw >> 11;
  const int f  = fb * 16 + (l & 15);
  const int k0 = kb * 32 + (l >> 4) * 8;
  const float* src = W1 + ((size_t)e * D_ + k0) * F_ + f;
  us8 v;
#pragma unroll
  for (int j = 0; j < 8; ++j) v[j] = f2bf(src[(size_t)j * F_]);
  *reinterpret_cast<us8*>(W1F + ((size_t)gw * 64 + l) * 8) = v;
}

// W2 [E][F][D] f32 -> fragment-ordered bf16:
// dest[((e*64+fb)*32+db)*512 + l*8 + j] = bf16(W2[e][fb*32+(l>>4)*8+j][db*16+(l&15)])
__global__ void cvtW2_k(const float* __restrict__ W2, unsigned short* __restrict__ W2B) {
  const int gid = blockIdx.x * 256 + threadIdx.x;    // 1,048,576 total
  const int l  = gid & 63;
  const int db = (gid >> 6) & 31;
  const int fb = (gid >> 11) & 63;
  const int e  = gid >> 17;
  const int d  = db * 16 + (l & 15);
  const int f0 = fb * 32 + (l >> 4) * 8;
  const float* src = W2 + ((size_t)e * F_ + f0) * D_ + d;
  us8 v;
#pragma unroll
  for (int j = 0; j < 8; ++j) v[j] = f2bf(src[(size_t)j * D_]);
  *reinterpret_cast<us8*>(W2B + (size_t)gid * 8) = v;
}

// one wave per token: logits = x_row @ Wr, softmax fp32, top-2. NO atomics.
__global__ void router_k(const float* __restrict__ x, const float* __restrict__ Wr,
                         int* __restrict__ ridx, float* __restrict__ rw) {
  const int wid = threadIdx.x >> 6, lane = threadIdx.x & 63;
  const int t = blockIdx.x * 4 + wid;
  const float* xr = x + (size_t)t * D_ + lane * 8;
  const float4 xa = *reinterpret_cast<const float4*>(xr);
  const float4 xb = *reinterpret_cast<const float4*>(xr + 4);
  float xv[8] = {xa.x, xa.y, xa.z, xa.w, xb.x, xb.y, xb.z, xb.w};
  float lg[8] = {0, 0, 0, 0, 0, 0, 0, 0};
#pragma unroll
  for (int j = 0; j < 8; ++j) {
    const float* wr = Wr + (size_t)(lane * 8 + j) * E_;
    float4 w0 = *reinterpret_cast<const float4*>(wr);
    float4 w1 = *reinterpret_cast<const float4*>(wr + 4);
    lg[0] += xv[j] * w0.x; lg[1] += xv[j] * w0.y; lg[2] += xv[j] * w0.z; lg[3] += xv[j] * w0.w;
    lg[4] += xv[j] * w1.x; lg[5] += xv[j] * w1.y; lg[6] += xv[j] * w1.z; lg[7] += xv[j] * w1.w;
  }
#pragma unroll
  for (int off = 32; off; off >>= 1) {
#pragma unroll
    for (int q = 0; q < 8; ++q) lg[q] += __shfl_xor(lg[q], off);
  }
  if (lane == 0) {
    float m = lg[0];
#pragma unroll
    for (int q = 1; q < 8; ++q) m = fmaxf(m, lg[q]);
    float p[8]; float s = 0.f;
#pragma unroll
    for (int q = 0; q < 8; ++q) { p[q] = expf(lg[q] - m); s += p[q]; }
    float inv = 1.f / s;
    int e1 = 0;
#pragma unroll
    for (int q = 1; q < 8; ++q) if (p[q] > p[e1]) e1 = q;
    int e2 = (e1 == 0) ? 1 : 0;
#pragma unroll
    for (int q = 0; q < 8; ++q) { if (q == e1) continue; if (p[q] > p[e2]) e2 = q; }
    ridx[2 * t] = e1; ridx[2 * t + 1] = e2;
    rw[2 * t] = p[e1] * inv; rw[2 * t + 1] = p[e2] * inv;
  }
}

// single block: counts, 128-padded offsets, zero cursors
__global__ void count_k(const int* __restrict__ ridx, int* __restrict__ ctrl) {
  __shared__ int h[E_];
  const int tid = threadIdx.x;   // 1024
  if (tid < E_) h[tid] = 0;
  __syncthreads();
  int c0=0,c1=0,c2=0,c3=0,c4=0,c5=0,c6=0,c7=0;
  for (int i = tid; i < 2 * N_TOK; i += 1024) {
    int v = ridx[i];
    c0 += (v == 0); c1 += (v == 1); c2 += (v == 2); c3 += (v == 3);
    c4 += (v == 4); c5 += (v == 5); c6 += (v == 6); c7 += (v == 7);
  }
  atomicAdd(&h[0], c0); atomicAdd(&h[1], c1); atomicAdd(&h[2], c2); atomicAdd(&h[3], c3);
  atomicAdd(&h[4], c4); atomicAdd(&h[5], c5); atomicAdd(&h[6], c6); atomicAdd(&h[7], c7);
  __syncthreads();
  if (tid == 0) {
    int a = 0;
    for (int e = 0; e < E_; ++e) {
      ctrl[e] = h[e];
      ctrl[8 + e] = a;
      a += (h[e] + 127) & ~127;
      ctrl[16 + e] = 0;
    }
    ctrl[24] = a;
  }
}

// per-block LDS ranks + 8 global atomics per block
__global__ void scatter_k(const int* __restrict__ ridx, const float* __restrict__ rw,
                          int* __restrict__ ctrl, int* __restrict__ ptok,
                          float* __restrict__ pgate) {
  __shared__ int h[E_], base[E_];
  const int tid = threadIdx.x;                 // 512
  const int g = blockIdx.x * 512 + tid;        // entry id
  if (tid < E_) h[tid] = 0;
  __syncthreads();
  const int e = ridx[g];
  const int r = atomicAdd(&h[e], 1);           // LDS atomic
  __syncthreads();
  if (tid < E_) base[tid] = atomicAdd(&ctrl[16 + tid], h[tid]);
  __syncthreads();
  const int pos = ctrl[8 + e] + base[e] + r;
  ptok[pos] = g >> 1;
  pgate[pos] = rw[g];
}

// gathered activations, FRAGMENT-ORDERED: XpF[sb][kb][64 l][8 j]:
// lane l holds x[tok(sb*16 + (l&15))][kb*32 + (l>>4)*8 + j]. Pad slots -> 0.
__global__ void gather_k(const float* __restrict__ x, const int* __restrict__ ptok,
                         const int* __restrict__ ctrl, unsigned short* __restrict__ XpF) {
  const int sb = blockIdx.x * 4 + (threadIdx.x >> 6);   // slot-block, 4160 total
  const int l  = threadIdx.x & 63;
  const int slot = sb * 16 + (l & 15);
  bool valid = false;
#pragma unroll
  for (int e = 0; e < E_; ++e) {
    int off = ctrl[8 + e], c = ctrl[e];
    valid = valid || (slot >= off && slot < off + c);
  }
  const int tok = valid ? ptok[slot] : 0;
  const int g = l >> 4;
  unsigned short* dst = XpF + ((size_t)sb * 16) * 512 + l * 8;
#pragma unroll
  for (int kb = 0; kb < 16; ++kb) {
    us8 v = (us8){0, 0, 0, 0, 0, 0, 0, 0};
    if (valid) {
      const float* src = x + (size_t)tok * D_ + kb * 32 + g * 8;
      float4 a = *reinterpret_cast<const float4*>(src);
      float4 b = *reinterpret_cast<const float4*>(src + 4);
      v[0] = f2bf(a.x); v[1] = f2bf(a.y); v[2] = f2bf(a.z); v[3] = f2bf(a.w);
      v[4] = f2bf(b.x); v[5] = f2bf(b.y); v[6] = f2bf(b.z); v[7] = f2bf(b.w);
    }
    *reinterpret_cast<us8*>(dst + (size_t)kb * 512) = v;
  }
}

// M=64, 1m x 8n. Continuous weight stream: next-jF W1 fragments issued BEFORE the
// Hs barrier and ride across it (lgkm-only barriers, no vmcnt drain). W2 kf-groups
// rotate 1-ahead. 256-VGPR class (launch_bounds 512,2): ILP over TLP, HK-style.
__global__ __launch_bounds__(512, 2) void ffn_k(
    const unsigned short* __restrict__ XpF,
    const unsigned short* __restrict__ W1F,   // [E][F/16][D/32][64][8]
    const unsigned short* __restrict__ W2B,   // [E][F/32][D/16][64][8]
    const int* __restrict__ ptok, const float* __restrict__ pgate,
    const int* __restrict__ ctrl, float* __restrict__ out) {
  const int gid = blockIdx.x;
  const int e = gid & 7;                      // XCD + expert affinity
  const int cnt = ctrl[e];
  const int tile0 = (gid >> 3) * M_TILE;
  if (tile0 >= cnt) return;
  const int slot0 = ctrl[8 + e] + tile0;      // 64-aligned
  const int sb0 = slot0 >> 4;

  __shared__ unsigned short Xs[32768];        // 64 KB: [sb_local*16+kb][lane*8]
  __shared__ unsigned short Hs[8192];         // 16 KB: [row][ch^(row&15)][8]

  const int tid = threadIdx.x;
  const int wn = tid >> 6, lane = tid & 63;   // 8 waves = 8 n-slices
  const int lr = lane & 15, lg4 = lane >> 4;

  const unsigned short* w1e = W1F + (size_t)e * (F_ * D_);
  const unsigned short* W2e = W2B + (size_t)e * (F_ * D_);

  // ---- stage X panel once (64 KB linear DMA), overlap initial W1 prefetch
  {
    const char* xsrc = (const char*)(XpF + (size_t)sb0 * 8192);
#pragma unroll
    for (int i = 0; i < 8; ++i) {
      const int o = (i * 512 + tid) * 16;
      gload16(xsrc + o, (char*)Xs + o);
    }
  }
  // initial prefetch: jF=0, kb 0..7 for this wave's f-frag
  bf16x8 bwN[8];
  {
    const unsigned short* w1b0 = w1e + ((size_t)wn * 16) * 512 + lane * 8;
#pragma unroll
    for (int i = 0; i < 8; ++i)
      bwN[i] = *reinterpret_cast<const bf16x8*>(w1b0 + (size_t)i * 512);
  }
  asm volatile("s_waitcnt vmcnt(0)" ::: "memory");
  __builtin_amdgcn_s_barrier();

  f32x4 acc[4][4];                            // [mi rows][ni d-frags]
#pragma unroll
  for (int i = 0; i < 4; ++i)
#pragma unroll
    for (int j = 0; j < 4; ++j) acc[i][j] = {0.f, 0.f, 0.f, 0.f};

  for (int jF = 0; jF < F_; jF += 128) {
    const unsigned short* w1b = w1e + ((size_t)((jF >> 4) + wn) * 16) * 512 + lane * 8;
    const unsigned short* w2b = W2e + ((size_t)((jF >> 5) * 32 + wn * 4)) * 512 + lane * 8;

    f32x4 hacc[4];
#pragma unroll
    for (int i = 0; i < 4; ++i) hacc[i] = {0.f, 0.f, 0.f, 0.f};

    // issue kb 8..11
    bf16x8 bwC[4], bwD[4];
#pragma unroll
    for (int i = 0; i < 4; ++i)
      bwC[i] = *reinterpret_cast<const bf16x8*>(w1b + (size_t)(8 + i) * 512);
    // consume kb 0..3 (prefetched across previous barrier)
#pragma unroll
    for (int i = 0; i < 4; ++i)
#pragma unroll
      for (int mi = 0; mi < 4; ++mi) {
        bf16x8 af = *reinterpret_cast<const bf16x8*>(&Xs[(mi * 16 + i) * 512 + lane * 8]);
        hacc[mi] = __builtin_amdgcn_mfma_f32_16x16x32_bf16(af, bwN[i], hacc[mi], 0, 0, 0);
      }
    // issue kb 12..15
#pragma unroll
    for (int i = 0; i < 4; ++i)
      bwD[i] = *reinterpret_cast<const bf16x8*>(w1b + (size_t)(12 + i) * 512);
    // consume kb 4..7
#pragma unroll
    for (int i = 0; i < 4; ++i)
#pragma unroll
      for (int mi = 0; mi < 4; ++mi) {
        bf16x8 af = *reinterpret_cast<const bf16x8*>(&Xs[(mi * 16 + 4 + i) * 512 + lane * 8]);
        hacc[mi] = __builtin_amdgcn_mfma_f32_16x16x32_bf16(af, bwN[4 + i], hacc[mi], 0, 0, 0);
      }
    // issue GEMM2 kf=0 group
    bf16x8 b2A[4], b2B[4];
#pragma unroll
    for (int i = 0; i < 4; ++i)
      b2A[i] = *reinterpret_cast<const bf16x8*>(w2b + (size_t)i * 512);
    // consume kb 8..11
#pragma unroll
    for (int i = 0; i < 4; ++i)
#pragma unroll
      for (int mi = 0; mi < 4; ++mi) {
        bf16x8 af = *reinterpret_cast<const bf16x8*>(&Xs[(mi * 16 + 8 + i) * 512 + lane * 8]);
        hacc[mi] = __builtin_amdgcn_mfma_f32_16x16x32_bf16(af, bwC[i], hacc[mi], 0, 0, 0);
      }
    // issue GEMM2 kf=1 group
#pragma unroll
    for (int i = 0; i < 4; ++i)
      b2B[i] = *reinterpret_cast<const bf16x8*>(w2b + (size_t)(16384 + i * 512));
    // consume kb 12..15
#pragma unroll
    for (int i = 0; i < 4; ++i)
#pragma unroll
      for (int mi = 0; mi < 4; ++mi) {
        bf16x8 af = *reinterpret_cast<const bf16x8*>(&Xs[(mi * 16 + 12 + i) * 512 + lane * 8]);
        hacc[mi] = __builtin_amdgcn_mfma_f32_16x16x32_bf16(af, bwD[i], hacc[mi], 0, 0, 0);
      }

    // ---- fast GELU -> Hs (bf16), 16B-chunk XOR swizzle
#pragma unroll
    for (int mi = 0; mi < 4; ++mi)
#pragma unroll
      for (int r = 0; r < 4; ++r) {
        float v = hacc[mi][r];
        float u = v * v;
        float wv = v * fmaf(0.044715f, u, 1.0f);
        float z = __expf(-1.5957691216057308f * wv);
        float g = v * __frcp_rn(1.0f + z);
        const int row = mi * 16 + lg4 * 4 + r;
        const int col = wn * 16 + lr;
        const int ch = (col >> 3) ^ (row & 15);
        Hs[row * 128 + ch * 8 + (col & 7)] = f2bf(g);
      }

    // ---- prefetch NEXT jF's W1 kb0..7: rides across both barriers + GEMM2
    if (jF < F_ - 128) {
      const unsigned short* w1n = w1b + 65536;   // fb += 8
#pragma unroll
      for (int i = 0; i < 8; ++i)
        bwN[i] = *reinterpret_cast<const bf16x8*>(w1n + (size_t)i * 512);
    }

    lbar();   // Hs writes visible; vmcnt NOT drained

    // ---- GEMM2: A from Hs (swizzled), B 1 kf-group ahead
#pragma unroll
    for (int kf = 0; kf < 4; ++kf) {
      bf16x8 bcur[4];
#pragma unroll
      for (int i = 0; i < 4; ++i) bcur[i] = (kf & 1) ? b2B[i] : b2A[i];
      if (kf < 2) {
        // issue kf+2 group into the buffer just freed
#pragma unroll
        for (int i = 0; i < 4; ++i) {
          bf16x8 nv = *reinterpret_cast<const bf16x8*>(w2b + (size_t)((kf + 2) * 16384 + i * 512));
          if (kf & 1) b2B[i] = nv; else b2A[i] = nv;
        }
      }
      bf16x8 ah[4];
#pragma unroll
      for (int mi = 0; mi < 4; ++mi) {
        const int row = mi * 16 + lr;
        const int ch = (kf * 4 + lg4) ^ (row & 15);
        ah[mi] = *reinterpret_cast<const bf16x8*>(&Hs[row * 128 + ch * 8]);
      }
#pragma unroll
      for (int mi = 0; mi < 4; ++mi)
#pragma unroll
        for (int ni = 0; ni < 4; ++ni)
          acc[mi][ni] = __builtin_amdgcn_mfma_f32_16x16x32_bf16(ah[mi], bcur[ni], acc[mi][ni], 0, 0, 0);
    }

    lbar();   // all Hs reads done before next iteration's writes
  }

  // ---- epilogue: gate from global, atomic-add (exactly 2 adds/elem -> deterministic)
  const int rowLim = cnt - tile0;
#pragma unroll
  for (int mi = 0; mi < 4; ++mi) {
#pragma unroll
    for (int r = 0; r < 4; ++r) {
      const int row = mi * 16 + lg4 * 4 + r;
      if (row < rowLim) {
        const int tok = ptok[slot0 + row];
        const float gt = pgate[slot0 + row];
        float* orow = out + (size_t)tok * D_ + wn * 64 + lr;
#pragma unroll
        for (int ni = 0; ni < 4; ++ni)
          atomicAdd(orow + ni * 16, gt * acc[mi][ni][r]);
      }
    }
  }
}

extern "C" void kernel_launch(void* const* d_in, const int* in_sizes, int n_in,
                              void* d_out, int out_size, void* d_ws, size_t ws_size,
                              hipStream_t stream) {
  const float* x  = (const float*)d_in[0];
  const float* Wr = (const float*)d_in[1];
  const float* W1 = (const float*)d_in[2];
  const float* W2 = (const float*)d_in[3];
  float* out = (float*)d_out;

  char* w = (char*)d_ws;
  unsigned short* W1F = (unsigned short*)(w);                    // 16 MiB frag-ordered
  unsigned short* W2B = (unsigned short*)(w + 16777216);         // 16 MiB frag-ordered
  unsigned short* XpF = (unsigned short*)(w + 33554432);         // 65 MiB frag-ordered
  int*   ridx  = (int*)  (w + 101711872);
  float* rwgt  = (float*)(w + 101974016);
  int*   ptok  = (int*)  (w + 102236160);
  float* pgate = (float*)(w + 102502400);
  int*   ctrl  = (int*)  (w + 102768640);

  cvtW1_k<<<4096, 256, 0, stream>>>(W1, W1F);
  cvtW2_k<<<4096, 256, 0, stream>>>(W2, W2B);
  router_k<<<N_TOK / 4, 256, 0, stream>>>(x, Wr, ridx, rwgt);
  count_k<<<1, 1024, 0, stream>>>(ridx, ctrl);
  scatter_k<<<N_TOK * 2 / 512, 512, 0, stream>>>(ridx, rwgt, ctrl, ptok, pgate);
  gather_k<<<NSLOT_MAX / 16 / 4, 256, 0, stream>>>(x, ptok, ctrl, XpF);
  hipMemsetAsync(out, 0, (size_t)out_size * sizeof(float), stream);
  ffn_k<<<8192, 512, 0, stream>>>(XpF, W1F, W2B, ptok, pgate, ctrl, out);
}